// Round 1
// baseline (1336.574 us; speedup 1.0000x reference)
//
#include <hip/hip_runtime.h>

#define NN 100000
#define NE 1600000
#define HID 128
#define NG 64
#define BN_EPS 1e-5f
#define NCHUNK 391   // ceil(100000/256)

// ---------------- CSR build ----------------
__global__ __launch_bounds__(256) void hist_kernel(const int* __restrict__ dst, int* __restrict__ deg) {
    int e = blockIdx.x * 256 + threadIdx.x;
    if (e < NE) atomicAdd(&deg[dst[e]], 1);
}

__global__ __launch_bounds__(256) void chunk_reduce(const int* __restrict__ deg, int* __restrict__ csumA) {
    __shared__ int s[256];
    int i = blockIdx.x * 256 + threadIdx.x;
    s[threadIdx.x] = (i < NN) ? deg[i] : 0;
    __syncthreads();
    for (int off = 128; off > 0; off >>= 1) {
        if (threadIdx.x < off) s[threadIdx.x] += s[threadIdx.x + off];
        __syncthreads();
    }
    if (threadIdx.x == 0) csumA[blockIdx.x] = s[0];
}

__global__ __launch_bounds__(512) void scan_chunks(const int* __restrict__ csumA, int* __restrict__ csumE) {
    __shared__ int s[512];
    int t = threadIdx.x;
    int v = (t < NCHUNK) ? csumA[t] : 0;
    s[t] = v;
    __syncthreads();
    for (int off = 1; off < 512; off <<= 1) {
        int x = (t >= off) ? s[t - off] : 0;
        __syncthreads();
        s[t] += x;
        __syncthreads();
    }
    if (t < NCHUNK) csumE[t] = s[t] - v;   // exclusive
}

__global__ __launch_bounds__(256) void scan_write(const int* __restrict__ deg, const int* __restrict__ csumE,
                                                  int* __restrict__ rowptr, int* __restrict__ cursor) {
    __shared__ int s[256];
    int t = threadIdx.x;
    int i = blockIdx.x * 256 + t;
    int v = (i < NN) ? deg[i] : 0;
    s[t] = v;
    __syncthreads();
    for (int off = 1; off < 256; off <<= 1) {
        int x = (t >= off) ? s[t - off] : 0;
        __syncthreads();
        s[t] += x;
        __syncthreads();
    }
    int excl = csumE[blockIdx.x] + s[t] - v;
    if (i < NN) { rowptr[i] = excl; cursor[i] = excl; }
    if (i == NN - 1) rowptr[NN] = NE;
}

__global__ __launch_bounds__(256) void fill_csr(const int* __restrict__ src, const int* __restrict__ dst,
                                                int* __restrict__ cursor, int* __restrict__ col) {
    int e = blockIdx.x * 256 + threadIdx.x;
    if (e < NE) {
        int d = dst[e];
        int p = atomicAdd(&cursor[d], 1);
        col[p] = src[e];
    }
}

// ---------------- per-layer kernels ----------------
// z[i] = h[i] + sum_{j in N(i)} h[j]; half-wave (32 lanes, float4) per node, 8 nodes/block
__global__ __launch_bounds__(256) void agg_kernel(const float* __restrict__ h, const int* __restrict__ rowptr,
                                                  const int* __restrict__ col, float* __restrict__ z) {
    int node = blockIdx.x * 8 + (threadIdx.x >> 5);
    int l = threadIdx.x & 31;
    if (node >= NN) return;
    const float4* h4 = (const float4*)h;
    int s = rowptr[node], e = rowptr[node + 1];
    float4 acc = h4[(size_t)node * 32 + l];
    for (int j = s; j < e; ++j) {
        int c = col[j];
        float4 v = h4[(size_t)c * 32 + l];
        acc.x += v.x; acc.y += v.y; acc.z += v.z; acc.w += v.w;
    }
    ((float4*)z)[(size_t)node * 32 + l] = acc;
}

// C[M,128] = A[M,128] @ W[128,128] + bias, optional ReLU. fp32 vector GEMM.
// 64-row tile in LDS (pad stride 132), 256 thr as 16(tc)x16(tr), 4 rows x 8 cols per thread.
__global__ __launch_bounds__(256) void gemm128(const float* __restrict__ A, const float* __restrict__ W,
                                               const float* __restrict__ bias, float* __restrict__ C, int relu) {
    __shared__ float As[64 * 132];
    const int M = NN;
    int row0 = blockIdx.x * 64;
    int tid = threadIdx.x;
    {
        const float4* A4 = (const float4*)A;
        float4* As4 = (float4*)As;
        for (int it = 0; it < 8; ++it) {
            int idx = tid + it * 256;      // float4 slot in 64x128 tile
            int r = idx >> 5, c4 = idx & 31;
            int gr = row0 + r;
            float4 v = make_float4(0.f, 0.f, 0.f, 0.f);
            if (gr < M) v = A4[(size_t)gr * 32 + c4];
            As4[r * 33 + c4] = v;          // 132 floats = 33 float4 per row
        }
    }
    __syncthreads();
    int tc = tid & 15, tr = tid >> 4;
    float acc[4][8];
#pragma unroll
    for (int i = 0; i < 4; i++)
#pragma unroll
        for (int j = 0; j < 8; j++) acc[i][j] = 0.f;

    const float4* W4 = (const float4*)W;
#pragma unroll 4
    for (int k = 0; k < 128; ++k) {
        float4 w0 = W4[k * 32 + tc * 2];
        float4 w1 = W4[k * 32 + tc * 2 + 1];
        float wv[8] = {w0.x, w0.y, w0.z, w0.w, w1.x, w1.y, w1.z, w1.w};
        float av[4];
#pragma unroll
        for (int i = 0; i < 4; i++) av[i] = As[(tr * 4 + i) * 132 + k];
#pragma unroll
        for (int i = 0; i < 4; i++)
#pragma unroll
            for (int j = 0; j < 8; j++) acc[i][j] = fmaf(av[i], wv[j], acc[i][j]);
    }
    float bv[8];
#pragma unroll
    for (int j = 0; j < 8; j++) bv[j] = bias[tc * 8 + j];
    float4* C4 = (float4*)C;
#pragma unroll
    for (int i = 0; i < 4; i++) {
        int gr = row0 + tr * 4 + i;
        if (gr >= M) continue;
        float4 o0, o1;
        o0.x = acc[i][0] + bv[0]; o0.y = acc[i][1] + bv[1];
        o0.z = acc[i][2] + bv[2]; o0.w = acc[i][3] + bv[3];
        o1.x = acc[i][4] + bv[4]; o1.y = acc[i][5] + bv[5];
        o1.z = acc[i][6] + bv[6]; o1.w = acc[i][7] + bv[7];
        if (relu) {
            o0.x = fmaxf(o0.x, 0.f); o0.y = fmaxf(o0.y, 0.f); o0.z = fmaxf(o0.z, 0.f); o0.w = fmaxf(o0.w, 0.f);
            o1.x = fmaxf(o1.x, 0.f); o1.y = fmaxf(o1.y, 0.f); o1.z = fmaxf(o1.z, 0.f); o1.w = fmaxf(o1.w, 0.f);
        }
        C4[(size_t)gr * 32 + tc * 2] = o0;
        C4[(size_t)gr * 32 + tc * 2 + 1] = o1;
    }
}

// per-column sum / sumsq over rows (axis 0)
__global__ __launch_bounds__(256) void colstats(const float* __restrict__ Z, float* __restrict__ csum,
                                                float* __restrict__ csq) {
    int c = threadIdx.x & 127;
    int half = threadIdx.x >> 7;
    int r0 = blockIdx.x * 256;
    float s = 0.f, q = 0.f;
    for (int rr = half; rr < 256; rr += 2) {
        int r = r0 + rr;
        if (r < NN) {
            float v = Z[(size_t)r * HID + c];
            s += v; q += v * v;
        }
    }
    __shared__ float ls[256], lq[256];
    ls[threadIdx.x] = s; lq[threadIdx.x] = q;
    __syncthreads();
    if (half == 0) {
        s = ls[c] + ls[c + 128];
        q = lq[c] + lq[c + 128];
        atomicAdd(&csum[c], s);
        atomicAdd(&csq[c], q);
    }
}

__global__ void bn_fin(const float* __restrict__ csum, const float* __restrict__ csq,
                       const float* __restrict__ gamma, const float* __restrict__ beta, float* __restrict__ ss) {
    int c = threadIdx.x;
    float mu = csum[c] * (1.f / NN);
    float var = csq[c] * (1.f / NN) - mu * mu;
    float sc = gamma[c] * rsqrtf(var + BN_EPS);
    ss[c] = sc;
    ss[128 + c] = beta[c] - mu * sc;
}

__global__ __launch_bounds__(256) void bn_relu(const float* __restrict__ Z, const float* __restrict__ ss,
                                               float* __restrict__ H) {
    int i = blockIdx.x * 256 + threadIdx.x;   // float4 index
    if (i >= NN * 32) return;
    const float4* Z4 = (const float4*)Z;
    const float4* S4 = (const float4*)ss;
    float4* H4 = (float4*)H;
    int c4 = i & 31;
    float4 sc = S4[c4], sh = S4[32 + c4];
    float4 v = Z4[i];
    v.x = fmaxf(fmaf(v.x, sc.x, sh.x), 0.f);
    v.y = fmaxf(fmaf(v.y, sc.y, sh.y), 0.f);
    v.z = fmaxf(fmaf(v.z, sc.z, sh.z), 0.f);
    v.w = fmaxf(fmaf(v.w, sc.w, sh.w), 0.f);
    H4[i] = v;
}

// ---------------- pooling ----------------
__global__ void find_starts(const int* __restrict__ batch, int* __restrict__ starts) {
    int g = threadIdx.x;
    if (g > NG) return;
    int lo = 0, hi = NN;
    while (lo < hi) {
        int mid = (lo + hi) >> 1;
        if (batch[mid] < g) lo = mid + 1; else hi = mid;
    }
    starts[g] = lo;
}

__global__ __launch_bounds__(128) void pool_partial(const float* __restrict__ H, const int* __restrict__ starts,
                                                    float* __restrict__ gsum) {
    int g = blockIdx.x, slice = blockIdx.y, t = threadIdx.x;
    int s = starts[g], e = starts[g + 1];
    int len = e - s;
    if (len <= 0) return;
    int chunk = (len + 7) >> 3;
    int a = s + slice * chunk;
    int b = min(e, a + chunk);
    if (a >= b) return;
    float acc = 0.f;
    for (int r = a; r < b; ++r) acc += H[(size_t)r * HID + t];
    atomicAdd(&gsum[g * HID + t], acc);
}

__global__ void pool_final(const float* __restrict__ gsum, const int* __restrict__ starts, float* __restrict__ outG) {
    int g = blockIdx.x, t = threadIdx.x;
    float cnt = (float)(starts[g + 1] - starts[g]);
    cnt = fmaxf(cnt, 1.f);
    outG[g * HID + t] = gsum[g * HID + t] / cnt;
}

extern "C" void kernel_launch(void* const* d_in, const int* in_sizes, int n_in,
                              void* d_out, int out_size, void* d_ws, size_t ws_size,
                              hipStream_t stream) {
    const float* x = (const float*)d_in[0];
    const int* ei = (const int*)d_in[1];
    const int* batch = (const int*)d_in[2];
    const float* W1 = (const float*)d_in[3];
    const float* b1 = (const float*)d_in[4];
    const float* W2 = (const float*)d_in[5];
    const float* b2 = (const float*)d_in[6];
    const float* gamma = (const float*)d_in[7];
    const float* beta = (const float*)d_in[8];
    float* out = (float*)d_out;                         // node embeddings region (also scratch slot S2)
    float* outG = out + (size_t)NN * HID;               // graph embeddings region

    float* S0 = (float*)d_ws;
    float* S1 = S0 + (size_t)NN * HID;
    int* col = (int*)(S1 + (size_t)NN * HID);
    int* rowptr = col + NE;          // 100001 used, 100004 reserved
    int* cursor = rowptr + 100004;   // 100000
    int* deg = cursor + 100000;      // 100000
    int* csumA = deg + 100000;       // 512
    int* csumE = csumA + 512;        // 512
    int* starts = csumE + 512;       // 80 reserved (65 used)
    float* stats = (float*)(starts + 80);   // 256 (sum | sumsq)
    float* ss = stats + 256;                // 256 (scale | shift)
    float* gsum = ss + 256;                 // 8192

    const int* srcv = ei;
    const int* dstv = ei + NE;

    // CSR build (once; reused by all 3 layers)
    hipMemsetAsync(deg, 0, NN * sizeof(int), stream);
    hist_kernel<<<(NE + 255) / 256, 256, 0, stream>>>(dstv, deg);
    chunk_reduce<<<NCHUNK, 256, 0, stream>>>(deg, csumA);
    scan_chunks<<<1, 512, 0, stream>>>(csumA, csumE);
    scan_write<<<NCHUNK, 256, 0, stream>>>(deg, csumE, rowptr, cursor);
    fill_csr<<<(NE + 255) / 256, 256, 0, stream>>>(srcv, dstv, cursor, col);

    // buffer rotation: S2 = out (node region)
    const float* hin[3] = {x, S0, out};
    float* zb[3]  = {S0, S1, S0};
    float* z1b[3] = {S1, out, S1};
    float* z2b[3] = {out, S1, S0};
    float* hb[3]  = {S0, out, out};

    for (int l = 0; l < 3; ++l) {
        agg_kernel<<<NN / 8, 256, 0, stream>>>(hin[l], rowptr, col, zb[l]);
        gemm128<<<(NN + 63) / 64, 256, 0, stream>>>(zb[l], W1 + l * HID * HID, b1 + l * HID, z1b[l], 1);
        gemm128<<<(NN + 63) / 64, 256, 0, stream>>>(z1b[l], W2 + l * HID * HID, b2 + l * HID, z2b[l], 0);
        hipMemsetAsync(stats, 0, 256 * sizeof(float), stream);
        colstats<<<NCHUNK, 256, 0, stream>>>(z2b[l], stats, stats + 128);
        bn_fin<<<1, 128, 0, stream>>>(stats, stats + 128, gamma + l * HID, beta + l * HID, ss);
        bn_relu<<<NN * 32 / 256, 256, 0, stream>>>(z2b[l], ss, hb[l]);
    }

    find_starts<<<1, 128, 0, stream>>>(batch, starts);
    hipMemsetAsync(gsum, 0, NG * HID * sizeof(float), stream);
    pool_partial<<<dim3(NG, 8), 128, 0, stream>>>(out, starts, gsum);
    pool_final<<<NG, 128, 0, stream>>>(gsum, starts, outG);
}

// Round 2
// 1224.973 us; speedup vs baseline: 1.0911x; 1.0911x over previous
//
#include <hip/hip_runtime.h>
#include <hip/hip_bf16.h>

#define NN 100000
#define NE 1600000
#define HID 128
#define NG 64
#define BN_EPS 1e-5f
#define NCHUNK 391   // ceil(100000/256)

typedef __attribute__((ext_vector_type(8))) short short8;
typedef __attribute__((ext_vector_type(4))) float floatx4;

// ---------------- CSR build ----------------
__global__ __launch_bounds__(256) void hist_kernel(const int* __restrict__ dst, int* __restrict__ deg) {
    int e = blockIdx.x * 256 + threadIdx.x;
    if (e < NE) atomicAdd(&deg[dst[e]], 1);
}

__global__ __launch_bounds__(256) void chunk_reduce(const int* __restrict__ deg, int* __restrict__ csumA) {
    __shared__ int s[256];
    int i = blockIdx.x * 256 + threadIdx.x;
    s[threadIdx.x] = (i < NN) ? deg[i] : 0;
    __syncthreads();
    for (int off = 128; off > 0; off >>= 1) {
        if (threadIdx.x < off) s[threadIdx.x] += s[threadIdx.x + off];
        __syncthreads();
    }
    if (threadIdx.x == 0) csumA[blockIdx.x] = s[0];
}

__global__ __launch_bounds__(512) void scan_chunks(const int* __restrict__ csumA, int* __restrict__ csumE) {
    __shared__ int s[512];
    int t = threadIdx.x;
    int v = (t < NCHUNK) ? csumA[t] : 0;
    s[t] = v;
    __syncthreads();
    for (int off = 1; off < 512; off <<= 1) {
        int x = (t >= off) ? s[t - off] : 0;
        __syncthreads();
        s[t] += x;
        __syncthreads();
    }
    if (t < NCHUNK) csumE[t] = s[t] - v;   // exclusive
}

__global__ __launch_bounds__(256) void scan_write(const int* __restrict__ deg, const int* __restrict__ csumE,
                                                  int* __restrict__ rowptr, int* __restrict__ cursor) {
    __shared__ int s[256];
    int t = threadIdx.x;
    int i = blockIdx.x * 256 + t;
    int v = (i < NN) ? deg[i] : 0;
    s[t] = v;
    __syncthreads();
    for (int off = 1; off < 256; off <<= 1) {
        int x = (t >= off) ? s[t - off] : 0;
        __syncthreads();
        s[t] += x;
        __syncthreads();
    }
    int excl = csumE[blockIdx.x] + s[t] - v;
    if (i < NN) { rowptr[i] = excl; cursor[i] = excl; }
    if (i == NN - 1) rowptr[NN] = NE;
}

__global__ __launch_bounds__(256) void fill_csr(const int* __restrict__ src, const int* __restrict__ dst,
                                                int* __restrict__ cursor, int* __restrict__ col) {
    int e = blockIdx.x * 256 + threadIdx.x;
    if (e < NE) {
        int d = dst[e];
        int p = atomicAdd(&cursor[d], 1);
        col[p] = src[e];
    }
}

// ---------------- aggregation ----------------
__global__ __launch_bounds__(256) void agg_kernel(const float* __restrict__ h, const int* __restrict__ rowptr,
                                                  const int* __restrict__ col, float* __restrict__ z) {
    int node = blockIdx.x * 8 + (threadIdx.x >> 5);
    int l = threadIdx.x & 31;
    if (node >= NN) return;
    const float4* h4 = (const float4*)h;
    int s = rowptr[node], e = rowptr[node + 1];
    float4 acc = h4[(size_t)node * 32 + l];
    for (int j = s; j < e; ++j) {
        int c = col[j];
        float4 v = h4[(size_t)c * 32 + l];
        acc.x += v.x; acc.y += v.y; acc.z += v.z; acc.w += v.w;
    }
    ((float4*)z)[(size_t)node * 32 + l] = acc;
}

// ---------------- W pre-pack: fp32 [128][128] -> bf16 hi/lo planes in MFMA B-fragment order ----
// Slot layout: Wp[((t*4 + s)*64 + lane)*8 + j]  (ushort bf16), hi plane at 0, lo plane at +16384.
// Fragment: lane holds B[k = s*32 + (lane>>4)*8 + j][n = t*16 + (lane&15)].
__global__ __launch_bounds__(256) void pack_w(const float* __restrict__ W, unsigned short* __restrict__ Wp) {
    int t = blockIdx.x;            // n-tile 0..7
    int s = threadIdx.x >> 6;      // k-step 0..3
    int lane = threadIdx.x & 63;
    int n = t * 16 + (lane & 15);
    int k0 = s * 32 + (lane >> 4) * 8;
    unsigned short hi[8], lo[8];
#pragma unroll
    for (int j = 0; j < 8; ++j) {
        float v = W[(k0 + j) * 128 + n];
        __hip_bfloat16 hb = __float2bfloat16(v);
        float hf = __bfloat162float(hb);
        __hip_bfloat16 lb = __float2bfloat16(v - hf);
        hi[j] = *(unsigned short*)&hb;
        lo[j] = *(unsigned short*)&lb;
    }
    size_t base = (size_t)((t * 4 + s) * 64 + lane) * 8;
#pragma unroll
    for (int j = 0; j < 8; ++j) {
        Wp[base + j] = hi[j];
        Wp[16384 + base + j] = lo[j];
    }
}

// ---------------- split-bf16 MFMA GEMM: C[M,128] = A[M,128] @ W[128,128] + bias, opt ReLU ----
#define LDSP 136   // ushorts per LDS row (272 B): 272/4 % 32 == 4 -> only 2-way bank aliasing (free)
__global__ __launch_bounds__(256) void gemm_mfma(const float* __restrict__ A,
                                                 const unsigned short* __restrict__ Wp,
                                                 const float* __restrict__ bias,
                                                 float* __restrict__ C, int relu) {
    __shared__ unsigned short Ahi[64 * LDSP];
    __shared__ unsigned short Alo[64 * LDSP];
    int row0 = blockIdx.x * 64;
    int tid = threadIdx.x;
    // stage 64x128 fp32 tile, converting to bf16 hi/lo planes
    const float4* A4 = (const float4*)A;
#pragma unroll
    for (int it = 0; it < 8; ++it) {
        int idx = tid + it * 256;          // float4 slot
        int r = idx >> 5, c4 = idx & 31;
        int gr = row0 + r;
        float4 v = make_float4(0.f, 0.f, 0.f, 0.f);
        if (gr < NN) v = A4[(size_t)gr * 32 + c4];
        float vv[4] = {v.x, v.y, v.z, v.w};
        unsigned short h[4], lw[4];
#pragma unroll
        for (int e = 0; e < 4; ++e) {
            __hip_bfloat16 hb = __float2bfloat16(vv[e]);
            float hf = __bfloat162float(hb);
            __hip_bfloat16 lb = __float2bfloat16(vv[e] - hf);
            h[e] = *(unsigned short*)&hb;
            lw[e] = *(unsigned short*)&lb;
        }
        *(ushort4*)&Ahi[r * LDSP + c4 * 4] = make_ushort4(h[0], h[1], h[2], h[3]);
        *(ushort4*)&Alo[r * LDSP + c4 * 4] = make_ushort4(lw[0], lw[1], lw[2], lw[3]);
    }
    __syncthreads();

    int lane = tid & 63;
    int wave = tid >> 6;
    int m = lane & 15, quad = lane >> 4;
    int arow = wave * 16 + m;

    floatx4 acc[8];
#pragma unroll
    for (int t = 0; t < 8; ++t) acc[t] = (floatx4){0.f, 0.f, 0.f, 0.f};

#pragma unroll
    for (int s = 0; s < 4; ++s) {
        short8 ah = *(short8*)&Ahi[arow * LDSP + s * 32 + quad * 8];
        short8 al = *(short8*)&Alo[arow * LDSP + s * 32 + quad * 8];
#pragma unroll
        for (int t = 0; t < 8; ++t) {
            const short8 bh = *(const short8*)(Wp + ((size_t)((t * 4 + s) * 64 + lane)) * 8);
            const short8 bl = *(const short8*)(Wp + 16384 + ((size_t)((t * 4 + s) * 64 + lane)) * 8);
            acc[t] = __builtin_amdgcn_mfma_f32_16x16x32_bf16(ah, bh, acc[t], 0, 0, 0);
            acc[t] = __builtin_amdgcn_mfma_f32_16x16x32_bf16(al, bh, acc[t], 0, 0, 0);
            acc[t] = __builtin_amdgcn_mfma_f32_16x16x32_bf16(ah, bl, acc[t], 0, 0, 0);
        }
    }

    // epilogue: C/D layout col = t*16 + (lane&15), row = wave*16 + quad*4 + reg
#pragma unroll
    for (int t = 0; t < 8; ++t) {
        int colc = t * 16 + m;
        float bv = bias[colc];
#pragma unroll
        for (int r = 0; r < 4; ++r) {
            int grow = row0 + wave * 16 + quad * 4 + r;
            if (grow < NN) {
                float o = acc[t][r] + bv;
                if (relu) o = fmaxf(o, 0.f);
                C[(size_t)grow * HID + colc] = o;
            }
        }
    }
}

// ---------------- BN stats / apply ----------------
__global__ __launch_bounds__(256) void colstats(const float* __restrict__ Z, float* __restrict__ csum,
                                                float* __restrict__ csq) {
    int c = threadIdx.x & 127;
    int half = threadIdx.x >> 7;
    int r0 = blockIdx.x * 256;
    float s = 0.f, q = 0.f;
    for (int rr = half; rr < 256; rr += 2) {
        int r = r0 + rr;
        if (r < NN) {
            float v = Z[(size_t)r * HID + c];
            s += v; q += v * v;
        }
    }
    __shared__ float ls[256], lq[256];
    ls[threadIdx.x] = s; lq[threadIdx.x] = q;
    __syncthreads();
    if (half == 0) {
        s = ls[c] + ls[c + 128];
        q = lq[c] + lq[c + 128];
        atomicAdd(&csum[c], s);
        atomicAdd(&csq[c], q);
    }
}

__global__ void bn_fin(const float* __restrict__ csum, const float* __restrict__ csq,
                       const float* __restrict__ gamma, const float* __restrict__ beta, float* __restrict__ ss) {
    int c = threadIdx.x;
    float mu = csum[c] * (1.f / NN);
    float var = csq[c] * (1.f / NN) - mu * mu;
    float sc = gamma[c] * rsqrtf(var + BN_EPS);
    ss[c] = sc;
    ss[128 + c] = beta[c] - mu * sc;
}

__global__ __launch_bounds__(256) void bn_relu(const float* __restrict__ Z, const float* __restrict__ ss,
                                               float* __restrict__ H) {
    int i = blockIdx.x * 256 + threadIdx.x;   // float4 index
    if (i >= NN * 32) return;
    const float4* Z4 = (const float4*)Z;
    const float4* S4 = (const float4*)ss;
    float4* H4 = (float4*)H;
    int c4 = i & 31;
    float4 sc = S4[c4], sh = S4[32 + c4];
    float4 v = Z4[i];
    v.x = fmaxf(fmaf(v.x, sc.x, sh.x), 0.f);
    v.y = fmaxf(fmaf(v.y, sc.y, sh.y), 0.f);
    v.z = fmaxf(fmaf(v.z, sc.z, sh.z), 0.f);
    v.w = fmaxf(fmaf(v.w, sc.w, sh.w), 0.f);
    H4[i] = v;
}

// ---------------- pooling ----------------
__global__ void find_starts(const int* __restrict__ batch, int* __restrict__ starts) {
    int g = threadIdx.x;
    if (g > NG) return;
    int lo = 0, hi = NN;
    while (lo < hi) {
        int mid = (lo + hi) >> 1;
        if (batch[mid] < g) lo = mid + 1; else hi = mid;
    }
    starts[g] = lo;
}

__global__ __launch_bounds__(128) void pool_partial(const float* __restrict__ H, const int* __restrict__ starts,
                                                    float* __restrict__ gsum) {
    int g = blockIdx.x, slice = blockIdx.y, t = threadIdx.x;
    int s = starts[g], e = starts[g + 1];
    int len = e - s;
    if (len <= 0) return;
    int chunk = (len + 7) >> 3;
    int a = s + slice * chunk;
    int b = min(e, a + chunk);
    if (a >= b) return;
    float acc = 0.f;
    for (int r = a; r < b; ++r) acc += H[(size_t)r * HID + t];
    atomicAdd(&gsum[g * HID + t], acc);
}

__global__ void pool_final(const float* __restrict__ gsum, const int* __restrict__ starts, float* __restrict__ outG) {
    int g = blockIdx.x, t = threadIdx.x;
    float cnt = (float)(starts[g + 1] - starts[g]);
    cnt = fmaxf(cnt, 1.f);
    outG[g * HID + t] = gsum[g * HID + t] / cnt;
}

extern "C" void kernel_launch(void* const* d_in, const int* in_sizes, int n_in,
                              void* d_out, int out_size, void* d_ws, size_t ws_size,
                              hipStream_t stream) {
    const float* x = (const float*)d_in[0];
    const int* ei = (const int*)d_in[1];
    const int* batch = (const int*)d_in[2];
    const float* W1 = (const float*)d_in[3];
    const float* b1 = (const float*)d_in[4];
    const float* W2 = (const float*)d_in[5];
    const float* b2 = (const float*)d_in[6];
    const float* gamma = (const float*)d_in[7];
    const float* beta = (const float*)d_in[8];
    float* out = (float*)d_out;                         // node embeddings region (also scratch slot)
    float* outG = out + (size_t)NN * HID;               // graph embeddings region

    float* S0 = (float*)d_ws;
    float* S1 = S0 + (size_t)NN * HID;
    int* col = (int*)(S1 + (size_t)NN * HID);
    int* rowptr = col + NE;          // 100001 used, 100004 reserved
    int* cursor = rowptr + 100004;   // 100000
    int* deg = cursor + 100000;      // 100000
    int* csumA = deg + 100000;       // 512
    int* csumE = csumA + 512;        // 512
    int* starts = csumE + 512;       // 80 reserved (65 used)
    float* stats = (float*)(starts + 80);   // 256 (sum | sumsq)
    float* ss = stats + 256;                // 256 (scale | shift)
    float* gsum = ss + 256;                 // 8192
    unsigned short* Wp = (unsigned short*)(gsum + 8192);  // 6 matrices x 32768 ushorts = 384 KB

    const int* srcv = ei;
    const int* dstv = ei + NE;

    // CSR build (reused by all 3 layers)
    hipMemsetAsync(deg, 0, NN * sizeof(int), stream);
    hist_kernel<<<(NE + 255) / 256, 256, 0, stream>>>(dstv, deg);
    chunk_reduce<<<NCHUNK, 256, 0, stream>>>(deg, csumA);
    scan_chunks<<<1, 512, 0, stream>>>(csumA, csumE);
    scan_write<<<NCHUNK, 256, 0, stream>>>(deg, csumE, rowptr, cursor);
    fill_csr<<<(NE + 255) / 256, 256, 0, stream>>>(srcv, dstv, cursor, col);

    // pack all 6 weight matrices into bf16 hi/lo MFMA fragment order
    for (int l = 0; l < 3; ++l) {
        pack_w<<<8, 256, 0, stream>>>(W1 + l * HID * HID, Wp + (size_t)(2 * l) * 32768);
        pack_w<<<8, 256, 0, stream>>>(W2 + l * HID * HID, Wp + (size_t)(2 * l + 1) * 32768);
    }

    // buffer rotation: slot "out" doubles as scratch
    const float* hin[3] = {x, S0, out};
    float* zb[3]  = {S0, S1, S0};
    float* z1b[3] = {S1, out, S1};
    float* z2b[3] = {out, S1, S0};
    float* hb[3]  = {S0, out, out};

    const int ngemm = (NN + 63) / 64;
    for (int l = 0; l < 3; ++l) {
        agg_kernel<<<NN / 8, 256, 0, stream>>>(hin[l], rowptr, col, zb[l]);
        gemm_mfma<<<ngemm, 256, 0, stream>>>(zb[l], Wp + (size_t)(2 * l) * 32768, b1 + l * HID, z1b[l], 1);
        gemm_mfma<<<ngemm, 256, 0, stream>>>(z1b[l], Wp + (size_t)(2 * l + 1) * 32768, b2 + l * HID, z2b[l], 0);
        hipMemsetAsync(stats, 0, 256 * sizeof(float), stream);
        colstats<<<NCHUNK, 256, 0, stream>>>(z2b[l], stats, stats + 128);
        bn_fin<<<1, 128, 0, stream>>>(stats, stats + 128, gamma + l * HID, beta + l * HID, ss);
        bn_relu<<<NN * 32 / 256, 256, 0, stream>>>(z2b[l], ss, hb[l]);
    }

    find_starts<<<1, 128, 0, stream>>>(batch, starts);
    hipMemsetAsync(gsum, 0, NG * HID * sizeof(float), stream);
    pool_partial<<<dim3(NG, 8), 128, 0, stream>>>(out, starts, gsum);
    pool_final<<<NG, 128, 0, stream>>>(gsum, starts, outG);
}

// Round 3
// 1057.076 us; speedup vs baseline: 1.2644x; 1.1588x over previous
//
#include <hip/hip_runtime.h>
#include <hip/hip_bf16.h>

#define NN 100000
#define NE 1600000
#define HID 128
#define NG 64
#define BN_EPS 1e-5f
#define NCHUNK 391     // ceil(100000/256)
#define NBUCK 391      // buckets of 256 nodes (dst>>8)
#define EPB 8192       // edges per pair_scatter block
#define NSB 196        // ceil(NE/EPB)

typedef __attribute__((ext_vector_type(8))) short short8;
typedef __attribute__((ext_vector_type(4))) float floatx4;

// ---------------- bucketed CSR build ----------------
__global__ __launch_bounds__(1024) void bucket_hist(const int* __restrict__ dst, int* __restrict__ bcount) {
    __shared__ int h[NBUCK];
    for (int i = threadIdx.x; i < NBUCK; i += 1024) h[i] = 0;
    __syncthreads();
    int base = blockIdx.x * EPB;
#pragma unroll
    for (int it = 0; it < 8; ++it) {
        int e = base + it * 1024 + threadIdx.x;
        if (e < NE) atomicAdd(&h[dst[e] >> 8], 1);
    }
    __syncthreads();
    for (int i = threadIdx.x; i < NBUCK; i += 1024)
        if (h[i]) atomicAdd(&bcount[i], h[i]);
}

__global__ __launch_bounds__(512) void bucket_scan(const int* __restrict__ bcount, int* __restrict__ bbase,
                                                   int* __restrict__ bcursor) {
    __shared__ int s[512];
    int t = threadIdx.x;
    int v = (t < NBUCK) ? bcount[t] : 0;
    s[t] = v;
    __syncthreads();
    for (int off = 1; off < 512; off <<= 1) {
        int x = (t >= off) ? s[t - off] : 0;
        __syncthreads();
        s[t] += x;
        __syncthreads();
    }
    if (t < NBUCK) {
        int excl = s[t] - v;
        bbase[t] = excl;
        bcursor[t] = excl;
    }
    if (t == 0) bbase[NBUCK] = NE;
}

__global__ __launch_bounds__(1024) void pair_scatter(const int* __restrict__ src, const int* __restrict__ dst,
                                                     int* __restrict__ bcursor, int2* __restrict__ pairs) {
    __shared__ int h[NBUCK];
    __shared__ int base[NBUCK];
    __shared__ int cur[NBUCK];
    for (int i = threadIdx.x; i < NBUCK; i += 1024) h[i] = 0;
    __syncthreads();
    int e0 = blockIdx.x * EPB;
    int myd[8], mys[8];
#pragma unroll
    for (int it = 0; it < 8; ++it) {
        int e = e0 + it * 1024 + threadIdx.x;
        if (e < NE) {
            myd[it] = dst[e];
            mys[it] = src[e];
            atomicAdd(&h[myd[it] >> 8], 1);
        } else myd[it] = -1;
    }
    __syncthreads();
    for (int i = threadIdx.x; i < NBUCK; i += 1024) {
        base[i] = h[i] ? atomicAdd(&bcursor[i], h[i]) : 0;
        cur[i] = 0;
    }
    __syncthreads();
#pragma unroll
    for (int it = 0; it < 8; ++it) {
        if (myd[it] >= 0) {
            int b = myd[it] >> 8;
            int off = atomicAdd(&cur[b], 1);
            pairs[base[b] + off] = make_int2(myd[it], mys[it]);
        }
    }
}

// one block per bucket: degrees + local scan -> rowptr; scatter col within bucket window
__global__ __launch_bounds__(256) void bucket_build(const int2* __restrict__ pairs, const int* __restrict__ bbase,
                                                    int* __restrict__ rowptr, int* __restrict__ col) {
    __shared__ int deg[256];
    __shared__ int s[256];
    __shared__ int cur[256];
    int b = blockIdx.x, t = threadIdx.x;
    int pstart = bbase[b], pend = bbase[b + 1];
    deg[t] = 0;
    __syncthreads();
    for (int p = pstart + t; p < pend; p += 256)
        atomicAdd(&deg[pairs[p].x & 255], 1);
    __syncthreads();
    int v = deg[t];
    s[t] = v;
    __syncthreads();
    for (int off = 1; off < 256; off <<= 1) {
        int x = (t >= off) ? s[t - off] : 0;
        __syncthreads();
        s[t] += x;
        __syncthreads();
    }
    int excl = pstart + s[t] - v;
    int node = b * 256 + t;
    if (node < NN) rowptr[node] = excl;
    cur[t] = excl;
    __syncthreads();
    for (int p = pstart + t; p < pend; p += 256) {
        int2 pr = pairs[p];
        int pos = atomicAdd(&cur[pr.x & 255], 1);
        col[pos] = pr.y;
    }
    if (b == NBUCK - 1 && t == 0) rowptr[NN] = NE;
}

// ---------------- aggregation ----------------
__global__ __launch_bounds__(256) void agg_kernel(const float* __restrict__ h, const int* __restrict__ rowptr,
                                                  const int* __restrict__ col, float* __restrict__ z) {
    int node = blockIdx.x * 8 + (threadIdx.x >> 5);
    int l = threadIdx.x & 31;
    if (node >= NN) return;
    const float4* h4 = (const float4*)h;
    int s = rowptr[node], e = rowptr[node + 1];
    float4 acc = h4[(size_t)node * 32 + l];
    int j = s;
    for (; j + 3 < e; j += 4) {
        int c0 = col[j], c1 = col[j + 1], c2 = col[j + 2], c3 = col[j + 3];
        float4 v0 = h4[(size_t)c0 * 32 + l];
        float4 v1 = h4[(size_t)c1 * 32 + l];
        float4 v2 = h4[(size_t)c2 * 32 + l];
        float4 v3 = h4[(size_t)c3 * 32 + l];
        acc.x += v0.x + v1.x + v2.x + v3.x;
        acc.y += v0.y + v1.y + v2.y + v3.y;
        acc.z += v0.z + v1.z + v2.z + v3.z;
        acc.w += v0.w + v1.w + v2.w + v3.w;
    }
    for (; j < e; ++j) {
        int c = col[j];
        float4 v = h4[(size_t)c * 32 + l];
        acc.x += v.x; acc.y += v.y; acc.z += v.z; acc.w += v.w;
    }
    ((float4*)z)[(size_t)node * 32 + l] = acc;
}

// ---------------- W pre-pack: fp32 [128][128] -> bf16 hi/lo planes in MFMA B-fragment order ----
__global__ __launch_bounds__(256) void pack_w(const float* __restrict__ W, unsigned short* __restrict__ Wp) {
    int t = blockIdx.x;            // n-tile 0..7
    int s = threadIdx.x >> 6;      // k-step 0..3
    int lane = threadIdx.x & 63;
    int n = t * 16 + (lane & 15);
    int k0 = s * 32 + (lane >> 4) * 8;
    unsigned short hi[8], lo[8];
#pragma unroll
    for (int j = 0; j < 8; ++j) {
        float v = W[(k0 + j) * 128 + n];
        __hip_bfloat16 hb = __float2bfloat16(v);
        float hf = __bfloat162float(hb);
        __hip_bfloat16 lb = __float2bfloat16(v - hf);
        hi[j] = *(unsigned short*)&hb;
        lo[j] = *(unsigned short*)&lb;
    }
    size_t base = (size_t)((t * 4 + s) * 64 + lane) * 8;
#pragma unroll
    for (int j = 0; j < 8; ++j) {
        Wp[base + j] = hi[j];
        Wp[16384 + base + j] = lo[j];
    }
}

// ---------------- split-bf16 MFMA GEMM ----------------
#define LDSP 136
__global__ __launch_bounds__(256) void gemm_mfma(const float* __restrict__ A,
                                                 const unsigned short* __restrict__ Wp,
                                                 const float* __restrict__ bias,
                                                 float* __restrict__ C, int relu) {
    __shared__ unsigned short Ahi[64 * LDSP];
    __shared__ unsigned short Alo[64 * LDSP];
    int row0 = blockIdx.x * 64;
    int tid = threadIdx.x;
    const float4* A4 = (const float4*)A;
#pragma unroll
    for (int it = 0; it < 8; ++it) {
        int idx = tid + it * 256;
        int r = idx >> 5, c4 = idx & 31;
        int gr = row0 + r;
        float4 v = make_float4(0.f, 0.f, 0.f, 0.f);
        if (gr < NN) v = A4[(size_t)gr * 32 + c4];
        float vv[4] = {v.x, v.y, v.z, v.w};
        unsigned short h[4], lw[4];
#pragma unroll
        for (int e = 0; e < 4; ++e) {
            __hip_bfloat16 hb = __float2bfloat16(vv[e]);
            float hf = __bfloat162float(hb);
            __hip_bfloat16 lb = __float2bfloat16(vv[e] - hf);
            h[e] = *(unsigned short*)&hb;
            lw[e] = *(unsigned short*)&lb;
        }
        *(ushort4*)&Ahi[r * LDSP + c4 * 4] = make_ushort4(h[0], h[1], h[2], h[3]);
        *(ushort4*)&Alo[r * LDSP + c4 * 4] = make_ushort4(lw[0], lw[1], lw[2], lw[3]);
    }
    __syncthreads();

    int lane = tid & 63;
    int wave = tid >> 6;
    int m = lane & 15, quad = lane >> 4;
    int arow = wave * 16 + m;

    floatx4 acc[8];
#pragma unroll
    for (int t = 0; t < 8; ++t) acc[t] = (floatx4){0.f, 0.f, 0.f, 0.f};

#pragma unroll
    for (int s = 0; s < 4; ++s) {
        short8 ah = *(short8*)&Ahi[arow * LDSP + s * 32 + quad * 8];
        short8 al = *(short8*)&Alo[arow * LDSP + s * 32 + quad * 8];
#pragma unroll
        for (int t = 0; t < 8; ++t) {
            const short8 bh = *(const short8*)(Wp + ((size_t)((t * 4 + s) * 64 + lane)) * 8);
            const short8 bl = *(const short8*)(Wp + 16384 + ((size_t)((t * 4 + s) * 64 + lane)) * 8);
            acc[t] = __builtin_amdgcn_mfma_f32_16x16x32_bf16(ah, bh, acc[t], 0, 0, 0);
            acc[t] = __builtin_amdgcn_mfma_f32_16x16x32_bf16(al, bh, acc[t], 0, 0, 0);
            acc[t] = __builtin_amdgcn_mfma_f32_16x16x32_bf16(ah, bl, acc[t], 0, 0, 0);
        }
    }

#pragma unroll
    for (int t = 0; t < 8; ++t) {
        int colc = t * 16 + m;
        float bv = bias[colc];
#pragma unroll
        for (int r = 0; r < 4; ++r) {
            int grow = row0 + wave * 16 + quad * 4 + r;
            if (grow < NN) {
                float o = acc[t][r] + bv;
                if (relu) o = fmaxf(o, 0.f);
                C[(size_t)grow * HID + colc] = o;
            }
        }
    }
}

// ---------------- BN stats / apply ----------------
__global__ __launch_bounds__(256) void colstats(const float* __restrict__ Z, float* __restrict__ csum,
                                                float* __restrict__ csq) {
    int c = threadIdx.x & 127;
    int half = threadIdx.x >> 7;
    int r0 = blockIdx.x * 256;
    float s = 0.f, q = 0.f;
    for (int rr = half; rr < 256; rr += 2) {
        int r = r0 + rr;
        if (r < NN) {
            float v = Z[(size_t)r * HID + c];
            s += v; q += v * v;
        }
    }
    __shared__ float ls[256], lq[256];
    ls[threadIdx.x] = s; lq[threadIdx.x] = q;
    __syncthreads();
    if (half == 0) {
        s = ls[c] + ls[c + 128];
        q = lq[c] + lq[c + 128];
        atomicAdd(&csum[c], s);
        atomicAdd(&csq[c], q);
    }
}

__global__ void bn_fin(const float* __restrict__ csum, const float* __restrict__ csq,
                       const float* __restrict__ gamma, const float* __restrict__ beta, float* __restrict__ ss) {
    int c = threadIdx.x;
    float mu = csum[c] * (1.f / NN);
    float var = csq[c] * (1.f / NN) - mu * mu;
    float sc = gamma[c] * rsqrtf(var + BN_EPS);
    ss[c] = sc;
    ss[128 + c] = beta[c] - mu * sc;
}

__global__ __launch_bounds__(256) void bn_relu(const float* __restrict__ Z, const float* __restrict__ ss,
                                               float* __restrict__ H) {
    int i = blockIdx.x * 256 + threadIdx.x;
    if (i >= NN * 32) return;
    const float4* Z4 = (const float4*)Z;
    const float4* S4 = (const float4*)ss;
    float4* H4 = (float4*)H;
    int c4 = i & 31;
    float4 sc = S4[c4], sh = S4[32 + c4];
    float4 v = Z4[i];
    v.x = fmaxf(fmaf(v.x, sc.x, sh.x), 0.f);
    v.y = fmaxf(fmaf(v.y, sc.y, sh.y), 0.f);
    v.z = fmaxf(fmaf(v.z, sc.z, sh.z), 0.f);
    v.w = fmaxf(fmaf(v.w, sc.w, sh.w), 0.f);
    H4[i] = v;
}

// ---------------- pooling ----------------
__global__ void find_starts(const int* __restrict__ batch, int* __restrict__ starts) {
    int g = threadIdx.x;
    if (g > NG) return;
    int lo = 0, hi = NN;
    while (lo < hi) {
        int mid = (lo + hi) >> 1;
        if (batch[mid] < g) lo = mid + 1; else hi = mid;
    }
    starts[g] = lo;
}

__global__ __launch_bounds__(128) void pool_partial(const float* __restrict__ H, const int* __restrict__ starts,
                                                    float* __restrict__ gsum) {
    int g = blockIdx.x, slice = blockIdx.y, t = threadIdx.x;
    int s = starts[g], e = starts[g + 1];
    int len = e - s;
    if (len <= 0) return;
    int chunk = (len + 7) >> 3;
    int a = s + slice * chunk;
    int b = min(e, a + chunk);
    if (a >= b) return;
    float acc = 0.f;
    for (int r = a; r < b; ++r) acc += H[(size_t)r * HID + t];
    atomicAdd(&gsum[g * HID + t], acc);
}

__global__ void pool_final(const float* __restrict__ gsum, const int* __restrict__ starts, float* __restrict__ outG) {
    int g = blockIdx.x, t = threadIdx.x;
    float cnt = (float)(starts[g + 1] - starts[g]);
    cnt = fmaxf(cnt, 1.f);
    outG[g * HID + t] = gsum[g * HID + t] / cnt;
}

extern "C" void kernel_launch(void* const* d_in, const int* in_sizes, int n_in,
                              void* d_out, int out_size, void* d_ws, size_t ws_size,
                              hipStream_t stream) {
    const float* x = (const float*)d_in[0];
    const int* ei = (const int*)d_in[1];
    const int* batch = (const int*)d_in[2];
    const float* W1 = (const float*)d_in[3];
    const float* b1 = (const float*)d_in[4];
    const float* W2 = (const float*)d_in[5];
    const float* b2 = (const float*)d_in[6];
    const float* gamma = (const float*)d_in[7];
    const float* beta = (const float*)d_in[8];
    float* out = (float*)d_out;
    float* outG = out + (size_t)NN * HID;

    float* S0 = (float*)d_ws;
    float* S1 = S0 + (size_t)NN * HID;
    int* col = (int*)(S1 + (size_t)NN * HID);
    int* rowptr = col + NE;                 // 100001 used, 100004 reserved
    int* bcount = rowptr + 100004;          // 512
    int* bbase = bcount + 512;              // 512
    int* bcursor = bbase + 512;             // 512
    int* starts = bcursor + 512;            // 80 reserved (65 used)
    float* stats = (float*)(starts + 80);   // 256 (sum | sumsq)
    float* ss = stats + 256;                // 256 (scale | shift)
    float* gsum = ss + 256;                 // 8192
    unsigned short* Wp = (unsigned short*)(gsum + 8192);  // 6 x 32768 ushorts
    int2* pairs = (int2*)S1;                // aliases S1 (only used during CSR build)

    const int* srcv = ei;
    const int* dstv = ei + NE;

    // bucketed CSR build
    hipMemsetAsync(bcount, 0, 512 * sizeof(int), stream);
    bucket_hist<<<NSB, 1024, 0, stream>>>(dstv, bcount);
    bucket_scan<<<1, 512, 0, stream>>>(bcount, bbase, bcursor);
    pair_scatter<<<NSB, 1024, 0, stream>>>(srcv, dstv, bcursor, pairs);
    bucket_build<<<NBUCK, 256, 0, stream>>>(pairs, bbase, rowptr, col);

    // pack all 6 weight matrices into bf16 hi/lo MFMA fragment order
    for (int l = 0; l < 3; ++l) {
        pack_w<<<8, 256, 0, stream>>>(W1 + l * HID * HID, Wp + (size_t)(2 * l) * 32768);
        pack_w<<<8, 256, 0, stream>>>(W2 + l * HID * HID, Wp + (size_t)(2 * l + 1) * 32768);
    }

    // buffer rotation: slot "out" doubles as scratch
    const float* hin[3] = {x, S0, out};
    float* zb[3]  = {S0, S1, S0};
    float* z1b[3] = {S1, out, S1};
    float* z2b[3] = {out, S1, S0};
    float* hb[3]  = {S0, out, out};

    const int ngemm = (NN + 63) / 64;
    for (int l = 0; l < 3; ++l) {
        agg_kernel<<<NN / 8, 256, 0, stream>>>(hin[l], rowptr, col, zb[l]);
        gemm_mfma<<<ngemm, 256, 0, stream>>>(zb[l], Wp + (size_t)(2 * l) * 32768, b1 + l * HID, z1b[l], 1);
        gemm_mfma<<<ngemm, 256, 0, stream>>>(z1b[l], Wp + (size_t)(2 * l + 1) * 32768, b2 + l * HID, z2b[l], 0);
        hipMemsetAsync(stats, 0, 256 * sizeof(float), stream);
        colstats<<<NCHUNK, 256, 0, stream>>>(z2b[l], stats, stats + 128);
        bn_fin<<<1, 128, 0, stream>>>(stats, stats + 128, gamma + l * HID, beta + l * HID, ss);
        bn_relu<<<NN * 32 / 256, 256, 0, stream>>>(z2b[l], ss, hb[l]);
    }

    find_starts<<<1, 128, 0, stream>>>(batch, starts);
    hipMemsetAsync(gsum, 0, NG * HID * sizeof(float), stream);
    pool_partial<<<dim3(NG, 8), 128, 0, stream>>>(out, starts, gsum);
    pool_final<<<NG, 128, 0, stream>>>(gsum, starts, outG);
}

// Round 4
// 751.157 us; speedup vs baseline: 1.7794x; 1.4073x over previous
//
#include <hip/hip_runtime.h>
#include <hip/hip_bf16.h>

#define NN 100000
#define NE 1600000
#define HID 128
#define NG 64
#define BN_EPS 1e-5f
#define NBUCK 391      // buckets of 256 nodes (dst>>8)
#define EPB 8192       // edges per pair_scatter block
#define NSB 196        // ceil(NE/EPB)

typedef __attribute__((ext_vector_type(8))) short short8;
typedef __attribute__((ext_vector_type(4))) float floatx4;

__device__ inline unsigned short f2bf_bits(float v) {
    __hip_bfloat16 h = __float2bfloat16(v);
    unsigned short u;
    __builtin_memcpy(&u, &h, 2);
    return u;
}
__device__ inline float4 bf4_to_f4(ushort4 u) {
    float4 f;
    f.x = __uint_as_float((unsigned)u.x << 16);
    f.y = __uint_as_float((unsigned)u.y << 16);
    f.z = __uint_as_float((unsigned)u.z << 16);
    f.w = __uint_as_float((unsigned)u.w << 16);
    return f;
}

// ---------------- bucketed CSR build ----------------
__global__ __launch_bounds__(1024) void bucket_hist(const int* __restrict__ dst, int* __restrict__ bcount) {
    __shared__ int h[NBUCK];
    for (int i = threadIdx.x; i < NBUCK; i += 1024) h[i] = 0;
    __syncthreads();
    int base = blockIdx.x * EPB;
#pragma unroll
    for (int it = 0; it < 8; ++it) {
        int e = base + it * 1024 + threadIdx.x;
        if (e < NE) atomicAdd(&h[dst[e] >> 8], 1);
    }
    __syncthreads();
    for (int i = threadIdx.x; i < NBUCK; i += 1024)
        if (h[i]) atomicAdd(&bcount[i], h[i]);
}

__global__ __launch_bounds__(512) void bucket_scan(const int* __restrict__ bcount, int* __restrict__ bbase,
                                                   int* __restrict__ bcursor) {
    __shared__ int s[512];
    int t = threadIdx.x;
    int v = (t < NBUCK) ? bcount[t] : 0;
    s[t] = v;
    __syncthreads();
    for (int off = 1; off < 512; off <<= 1) {
        int x = (t >= off) ? s[t - off] : 0;
        __syncthreads();
        s[t] += x;
        __syncthreads();
    }
    if (t < NBUCK) {
        int excl = s[t] - v;
        bbase[t] = excl;
        bcursor[t] = excl;
    }
    if (t == 0) bbase[NBUCK] = NE;
}

__global__ __launch_bounds__(1024) void pair_scatter(const int* __restrict__ src, const int* __restrict__ dst,
                                                     int* __restrict__ bcursor, int2* __restrict__ pairs) {
    __shared__ int h[NBUCK];
    __shared__ int base[NBUCK];
    __shared__ int cur[NBUCK];
    for (int i = threadIdx.x; i < NBUCK; i += 1024) h[i] = 0;
    __syncthreads();
    int e0 = blockIdx.x * EPB;
    int myd[8], mys[8];
#pragma unroll
    for (int it = 0; it < 8; ++it) {
        int e = e0 + it * 1024 + threadIdx.x;
        if (e < NE) {
            myd[it] = dst[e];
            mys[it] = src[e];
            atomicAdd(&h[myd[it] >> 8], 1);
        } else myd[it] = -1;
    }
    __syncthreads();
    for (int i = threadIdx.x; i < NBUCK; i += 1024) {
        base[i] = h[i] ? atomicAdd(&bcursor[i], h[i]) : 0;
        cur[i] = 0;
    }
    __syncthreads();
#pragma unroll
    for (int it = 0; it < 8; ++it) {
        if (myd[it] >= 0) {
            int b = myd[it] >> 8;
            int off = atomicAdd(&cur[b], 1);
            pairs[base[b] + off] = make_int2(myd[it], mys[it]);
        }
    }
}

__global__ __launch_bounds__(256) void bucket_build(const int2* __restrict__ pairs, const int* __restrict__ bbase,
                                                    int* __restrict__ rowptr, int* __restrict__ col) {
    __shared__ int deg[256];
    __shared__ int s[256];
    __shared__ int cur[256];
    int b = blockIdx.x, t = threadIdx.x;
    int pstart = bbase[b], pend = bbase[b + 1];
    deg[t] = 0;
    __syncthreads();
    for (int p = pstart + t; p < pend; p += 256)
        atomicAdd(&deg[pairs[p].x & 255], 1);
    __syncthreads();
    int v = deg[t];
    s[t] = v;
    __syncthreads();
    for (int off = 1; off < 256; off <<= 1) {
        int x = (t >= off) ? s[t - off] : 0;
        __syncthreads();
        s[t] += x;
        __syncthreads();
    }
    int excl = pstart + s[t] - v;
    int node = b * 256 + t;
    if (node < NN) rowptr[node] = excl;
    cur[t] = excl;
    __syncthreads();
    for (int p = pstart + t; p < pend; p += 256) {
        int2 pr = pairs[p];
        int pos = atomicAdd(&cur[pr.x & 255], 1);
        col[pos] = pr.y;
    }
    if (b == NBUCK - 1 && t == 0) rowptr[NN] = NE;
}

// ---------------- fp32 -> bf16 row conversion (for x) ----------------
__global__ __launch_bounds__(256) void f2bf(const float* __restrict__ X, unsigned short* __restrict__ O) {
    int i = blockIdx.x * 256 + threadIdx.x;   // 8-element group
    if (i >= NN * 16) return;
    const float4* X4 = (const float4*)X;
    float4 a = X4[2 * i], b = X4[2 * i + 1];
    ushort4 h0 = make_ushort4(f2bf_bits(a.x), f2bf_bits(a.y), f2bf_bits(a.z), f2bf_bits(a.w));
    ushort4 h1 = make_ushort4(f2bf_bits(b.x), f2bf_bits(b.y), f2bf_bits(b.z), f2bf_bits(b.w));
    ((ushort4*)O)[2 * i] = h0;
    ((ushort4*)O)[2 * i + 1] = h1;
}

// ---------------- aggregation over bf16 rows ----------------
__global__ __launch_bounds__(256) void agg_bf(const unsigned short* __restrict__ hb, const int* __restrict__ rowptr,
                                              const int* __restrict__ col, float* __restrict__ z) {
    int node = blockIdx.x * 8 + (threadIdx.x >> 5);
    int l = threadIdx.x & 31;
    if (node >= NN) return;
    const ushort4* h4 = (const ushort4*)hb;   // 32 ushort4 per row
    int s = rowptr[node], e = rowptr[node + 1];
    float4 acc = bf4_to_f4(h4[(size_t)node * 32 + l]);
    int j = s;
    for (; j + 3 < e; j += 4) {
        int c0 = col[j], c1 = col[j + 1], c2 = col[j + 2], c3 = col[j + 3];
        float4 v0 = bf4_to_f4(h4[(size_t)c0 * 32 + l]);
        float4 v1 = bf4_to_f4(h4[(size_t)c1 * 32 + l]);
        float4 v2 = bf4_to_f4(h4[(size_t)c2 * 32 + l]);
        float4 v3 = bf4_to_f4(h4[(size_t)c3 * 32 + l]);
        acc.x += v0.x + v1.x + v2.x + v3.x;
        acc.y += v0.y + v1.y + v2.y + v3.y;
        acc.z += v0.z + v1.z + v2.z + v3.z;
        acc.w += v0.w + v1.w + v2.w + v3.w;
    }
    for (; j < e; ++j) {
        int c = col[j];
        float4 v = bf4_to_f4(h4[(size_t)c * 32 + l]);
        acc.x += v.x; acc.y += v.y; acc.z += v.z; acc.w += v.w;
    }
    ((float4*)z)[(size_t)node * 32 + l] = acc;
}

// ---------------- W pre-pack: fp32 [128][128] -> bf16 hi/lo planes in MFMA B-fragment order ----
// Wp[((t*4 + s)*64 + lane)*8 + j], hi plane at 0, lo plane at +16384 ushorts.
// lane holds B[k = s*32 + (lane>>4)*8 + j][n = t*16 + (lane&15)].
__global__ __launch_bounds__(256) void pack_w(const float* __restrict__ W, unsigned short* __restrict__ Wp) {
    int t = blockIdx.x;
    int s = threadIdx.x >> 6;
    int lane = threadIdx.x & 63;
    int n = t * 16 + (lane & 15);
    int k0 = s * 32 + (lane >> 4) * 8;
    size_t base = (size_t)((t * 4 + s) * 64 + lane) * 8;
#pragma unroll
    for (int j = 0; j < 8; ++j) {
        float v = W[(k0 + j) * 128 + n];
        __hip_bfloat16 hb = __float2bfloat16(v);
        float hf = __bfloat162float(hb);
        Wp[base + j] = f2bf_bits(v);
        Wp[16384 + base + j] = f2bf_bits(v - hf);
    }
}

__device__ inline void split8(const float* p, bool ok, short8& hi, short8& lo) {
    float v[8];
    if (ok) {
        float4 a = *(const float4*)p;
        float4 b = *(const float4*)(p + 4);
        v[0] = a.x; v[1] = a.y; v[2] = a.z; v[3] = a.w;
        v[4] = b.x; v[5] = b.y; v[6] = b.z; v[7] = b.w;
    } else {
#pragma unroll
        for (int j = 0; j < 8; ++j) v[j] = 0.f;
    }
#pragma unroll
    for (int j = 0; j < 8; ++j) {
        __hip_bfloat16 hb = __float2bfloat16(v[j]);
        float hf = __bfloat162float(hb);
        hi[j] = (short)f2bf_bits(v[j]);
        lo[j] = (short)f2bf_bits(v[j] - hf);
    }
}

// ---------------- split-bf16 MFMA GEMM, W in LDS, A direct-to-register ----------------
// 128 rows/block, 4 waves, each wave 2 strips of 16 rows. Optional fused column stats.
__global__ __launch_bounds__(256) void gemm_mfma(const float* __restrict__ A,
                                                 const unsigned short* __restrict__ Wp,
                                                 const float* __restrict__ bias,
                                                 float* __restrict__ C, int relu,
                                                 float* __restrict__ stats) {
    __shared__ unsigned short Ws[32768];   // 64 KB: hi [0,16384), lo [16384,32768)
    __shared__ float cs[256];
    int tid = threadIdx.x;
    {
        const uint4* Wg = (const uint4*)Wp;
        uint4* Wl = (uint4*)Ws;
#pragma unroll
        for (int it = 0; it < 16; ++it) Wl[tid + it * 256] = Wg[tid + it * 256];
    }
    if (stats) cs[tid] = 0.f;
    __syncthreads();

    int lane = tid & 63, wave = tid >> 6;
    int m = lane & 15, quad = lane >> 4;
    int row0 = blockIdx.x * 128;
    int r0 = row0 + wave * 32 + m;        // strip 0 row
    int r1 = r0 + 16;                     // strip 1 row
    bool ok0 = r0 < NN, ok1 = r1 < NN;
    const float* A0 = A + (size_t)r0 * HID;
    const float* A1 = A + (size_t)r1 * HID;

    floatx4 acc[2][8];
#pragma unroll
    for (int p = 0; p < 2; ++p)
#pragma unroll
        for (int t = 0; t < 8; ++t) acc[p][t] = (floatx4){0.f, 0.f, 0.f, 0.f};

#pragma unroll
    for (int s = 0; s < 4; ++s) {
        short8 ah0, al0, ah1, al1;
        split8(A0 + s * 32 + quad * 8, ok0, ah0, al0);
        split8(A1 + s * 32 + quad * 8, ok1, ah1, al1);
#pragma unroll
        for (int t = 0; t < 8; ++t) {
            short8 bh = *(short8*)&Ws[((t * 4 + s) * 64 + lane) * 8];
            short8 bl = *(short8*)&Ws[16384 + ((t * 4 + s) * 64 + lane) * 8];
            acc[0][t] = __builtin_amdgcn_mfma_f32_16x16x32_bf16(ah0, bh, acc[0][t], 0, 0, 0);
            acc[1][t] = __builtin_amdgcn_mfma_f32_16x16x32_bf16(ah1, bh, acc[1][t], 0, 0, 0);
            acc[0][t] = __builtin_amdgcn_mfma_f32_16x16x32_bf16(al0, bh, acc[0][t], 0, 0, 0);
            acc[1][t] = __builtin_amdgcn_mfma_f32_16x16x32_bf16(al1, bh, acc[1][t], 0, 0, 0);
            acc[0][t] = __builtin_amdgcn_mfma_f32_16x16x32_bf16(ah0, bl, acc[0][t], 0, 0, 0);
            acc[1][t] = __builtin_amdgcn_mfma_f32_16x16x32_bf16(ah1, bl, acc[1][t], 0, 0, 0);
        }
    }

    // epilogue: C row = row0 + wave*32 + p*16 + quad*4 + r, col = t*16 + m
#pragma unroll
    for (int t = 0; t < 8; ++t) {
        int colc = t * 16 + m;
        float bv = bias[colc];
        float csum = 0.f, csq = 0.f;
#pragma unroll
        for (int p = 0; p < 2; ++p) {
#pragma unroll
            for (int r = 0; r < 4; ++r) {
                int grow = row0 + wave * 32 + p * 16 + quad * 4 + r;
                if (grow < NN) {
                    float o = acc[p][t][r] + bv;
                    if (relu) o = fmaxf(o, 0.f);
                    C[(size_t)grow * HID + colc] = o;
                    csum += o; csq += o * o;
                }
            }
        }
        if (stats) {
            csum += __shfl_xor(csum, 16); csum += __shfl_xor(csum, 32);
            csq  += __shfl_xor(csq, 16);  csq  += __shfl_xor(csq, 32);
            if (quad == 0) {
                atomicAdd(&cs[colc], csum);
                atomicAdd(&cs[128 + colc], csq);
            }
        }
    }
    if (stats) {
        __syncthreads();
        atomicAdd(&stats[tid], cs[tid]);
    }
}

// ---------------- BN finalize / apply ----------------
__global__ void bn_fin(const float* __restrict__ csum, const float* __restrict__ csq,
                       const float* __restrict__ gamma, const float* __restrict__ beta, float* __restrict__ ss) {
    int c = threadIdx.x;
    float mu = csum[c] * (1.f / NN);
    float var = csq[c] * (1.f / NN) - mu * mu;
    float sc = gamma[c] * rsqrtf(var + BN_EPS);
    ss[c] = sc;
    ss[128 + c] = beta[c] - mu * sc;
}

// BN + ReLU, output bf16 rows (layers 0,1)
__global__ __launch_bounds__(256) void bn_relu_bf(const float* __restrict__ Z, const float* __restrict__ ss,
                                                  unsigned short* __restrict__ H) {
    int i = blockIdx.x * 256 + threadIdx.x;   // 8-col group
    if (i >= NN * 16) return;
    int g = i & 15;
    const float4* S4 = (const float4*)ss;
    float4 sc0 = S4[g * 2], sc1 = S4[g * 2 + 1];
    float4 sh0 = S4[32 + g * 2], sh1 = S4[32 + g * 2 + 1];
    const float4* Z4 = (const float4*)Z;
    float4 a = Z4[2 * i], b = Z4[2 * i + 1];
    a.x = fmaxf(fmaf(a.x, sc0.x, sh0.x), 0.f); a.y = fmaxf(fmaf(a.y, sc0.y, sh0.y), 0.f);
    a.z = fmaxf(fmaf(a.z, sc0.z, sh0.z), 0.f); a.w = fmaxf(fmaf(a.w, sc0.w, sh0.w), 0.f);
    b.x = fmaxf(fmaf(b.x, sc1.x, sh1.x), 0.f); b.y = fmaxf(fmaf(b.y, sc1.y, sh1.y), 0.f);
    b.z = fmaxf(fmaf(b.z, sc1.z, sh1.z), 0.f); b.w = fmaxf(fmaf(b.w, sc1.w, sh1.w), 0.f);
    ((ushort4*)H)[2 * i] = make_ushort4(f2bf_bits(a.x), f2bf_bits(a.y), f2bf_bits(a.z), f2bf_bits(a.w));
    ((ushort4*)H)[2 * i + 1] = make_ushort4(f2bf_bits(b.x), f2bf_bits(b.y), f2bf_bits(b.z), f2bf_bits(b.w));
}

// BN + ReLU, fp32 output (final layer)
__global__ __launch_bounds__(256) void bn_relu_f32(const float* __restrict__ Z, const float* __restrict__ ss,
                                                   float* __restrict__ H) {
    int i = blockIdx.x * 256 + threadIdx.x;
    if (i >= NN * 32) return;
    const float4* Z4 = (const float4*)Z;
    const float4* S4 = (const float4*)ss;
    float4* H4 = (float4*)H;
    int c4 = i & 31;
    float4 sc = S4[c4], sh = S4[32 + c4];
    float4 v = Z4[i];
    v.x = fmaxf(fmaf(v.x, sc.x, sh.x), 0.f);
    v.y = fmaxf(fmaf(v.y, sc.y, sh.y), 0.f);
    v.z = fmaxf(fmaf(v.z, sc.z, sh.z), 0.f);
    v.w = fmaxf(fmaf(v.w, sc.w, sh.w), 0.f);
    H4[i] = v;
}

// ---------------- pooling ----------------
__global__ void find_starts(const int* __restrict__ batch, int* __restrict__ starts) {
    int g = threadIdx.x;
    if (g > NG) return;
    int lo = 0, hi = NN;
    while (lo < hi) {
        int mid = (lo + hi) >> 1;
        if (batch[mid] < g) lo = mid + 1; else hi = mid;
    }
    starts[g] = lo;
}

__global__ __launch_bounds__(128) void pool_partial(const float* __restrict__ H, const int* __restrict__ starts,
                                                    float* __restrict__ gsum) {
    int g = blockIdx.x, slice = blockIdx.y, t = threadIdx.x;
    int s = starts[g], e = starts[g + 1];
    int len = e - s;
    if (len <= 0) return;
    int chunk = (len + 7) >> 3;
    int a = s + slice * chunk;
    int b = min(e, a + chunk);
    if (a >= b) return;
    float acc = 0.f;
    for (int r = a; r < b; ++r) acc += H[(size_t)r * HID + t];
    atomicAdd(&gsum[g * HID + t], acc);
}

__global__ void pool_final(const float* __restrict__ gsum, const int* __restrict__ starts, float* __restrict__ outG) {
    int g = blockIdx.x, t = threadIdx.x;
    float cnt = (float)(starts[g + 1] - starts[g]);
    cnt = fmaxf(cnt, 1.f);
    outG[g * HID + t] = gsum[g * HID + t] / cnt;
}

extern "C" void kernel_launch(void* const* d_in, const int* in_sizes, int n_in,
                              void* d_out, int out_size, void* d_ws, size_t ws_size,
                              hipStream_t stream) {
    const float* x = (const float*)d_in[0];
    const int* ei = (const int*)d_in[1];
    const int* batch = (const int*)d_in[2];
    const float* W1 = (const float*)d_in[3];
    const float* b1 = (const float*)d_in[4];
    const float* W2 = (const float*)d_in[5];
    const float* b2 = (const float*)d_in[6];
    const float* gamma = (const float*)d_in[7];
    const float* beta = (const float*)d_in[8];
    float* out = (float*)d_out;
    float* outG = out + (size_t)NN * HID;
    unsigned short* B0 = (unsigned short*)out;   // bf16 h, front half of node region

    float* S0 = (float*)d_ws;
    float* S1 = S0 + (size_t)NN * HID;
    int* col = (int*)(S1 + (size_t)NN * HID);
    int* rowptr = col + NE;                 // 100001 used, 100004 reserved
    int* bcount = rowptr + 100004;          // 512
    int* bbase = bcount + 512;              // 512
    int* bcursor = bbase + 512;             // 512
    int* starts = bcursor + 512;            // 80 reserved (65 used)
    float* stats = (float*)(starts + 80);   // 256 (sum | sumsq)
    float* ss = stats + 256;                // 256 (scale | shift)
    float* gsum = ss + 256;                 // 8192
    unsigned short* Wp = (unsigned short*)(gsum + 8192);  // 6 x 32768 ushorts
    int2* pairs = (int2*)S1;                // aliases S1 (CSR build only)

    const int* srcv = ei;
    const int* dstv = ei + NE;

    // bucketed CSR build
    hipMemsetAsync(bcount, 0, 512 * sizeof(int), stream);
    bucket_hist<<<NSB, 1024, 0, stream>>>(dstv, bcount);
    bucket_scan<<<1, 512, 0, stream>>>(bcount, bbase, bcursor);
    pair_scatter<<<NSB, 1024, 0, stream>>>(srcv, dstv, bcursor, pairs);
    bucket_build<<<NBUCK, 256, 0, stream>>>(pairs, bbase, rowptr, col);

    // pack weights; convert x to bf16
    for (int l = 0; l < 3; ++l) {
        pack_w<<<8, 256, 0, stream>>>(W1 + l * HID * HID, Wp + (size_t)(2 * l) * 32768);
        pack_w<<<8, 256, 0, stream>>>(W2 + l * HID * HID, Wp + (size_t)(2 * l + 1) * 32768);
    }
    f2bf<<<NN * 16 / 256, 256, 0, stream>>>(x, B0);

    const int ngemm = (NN + 127) / 128;
    for (int l = 0; l < 3; ++l) {
        agg_bf<<<NN / 8, 256, 0, stream>>>(B0, rowptr, col, S0);
        gemm_mfma<<<ngemm, 256, 0, stream>>>(S0, Wp + (size_t)(2 * l) * 32768, b1 + l * HID, S1, 1, nullptr);
        hipMemsetAsync(stats, 0, 256 * sizeof(float), stream);
        gemm_mfma<<<ngemm, 256, 0, stream>>>(S1, Wp + (size_t)(2 * l + 1) * 32768, b2 + l * HID, S0, 0, stats);
        bn_fin<<<1, 128, 0, stream>>>(stats, stats + 128, gamma + l * HID, beta + l * HID, ss);
        if (l < 2)
            bn_relu_bf<<<NN * 16 / 256, 256, 0, stream>>>(S0, ss, B0);
        else
            bn_relu_f32<<<NN * 32 / 256, 256, 0, stream>>>(S0, ss, out);
    }

    find_starts<<<1, 128, 0, stream>>>(batch, starts);
    hipMemsetAsync(gsum, 0, NG * HID * sizeof(float), stream);
    pool_partial<<<dim3(NG, 8), 128, 0, stream>>>(out, starts, gsum);
    pool_final<<<NG, 128, 0, stream>>>(gsum, starts, outG);
}

// Round 5
// 697.531 us; speedup vs baseline: 1.9161x; 1.0769x over previous
//
#include <hip/hip_runtime.h>
#include <hip/hip_bf16.h>

#define NN 100000
#define NE 1600000
#define HID 128
#define NG 64
#define BN_EPS 1e-5f
#define NBUCK 391      // buckets of 256 nodes (dst>>8)
#define EPB 8192       // edges per pair_scatter block
#define NSB 196        // ceil(NE/EPB)

typedef __attribute__((ext_vector_type(8))) short short8;
typedef __attribute__((ext_vector_type(4))) float floatx4;

__device__ inline unsigned short f2bf_bits(float v) {
    __hip_bfloat16 h = __float2bfloat16(v);
    unsigned short u;
    __builtin_memcpy(&u, &h, 2);
    return u;
}
__device__ inline float4 bf4_to_f4(ushort4 u) {
    float4 f;
    f.x = __uint_as_float((unsigned)u.x << 16);
    f.y = __uint_as_float((unsigned)u.y << 16);
    f.z = __uint_as_float((unsigned)u.z << 16);
    f.w = __uint_as_float((unsigned)u.w << 16);
    return f;
}

// ---------------- bucketed CSR build ----------------
__global__ __launch_bounds__(1024) void bucket_hist(const int* __restrict__ dst, int* __restrict__ bcount) {
    __shared__ int h[NBUCK];
    for (int i = threadIdx.x; i < NBUCK; i += 1024) h[i] = 0;
    __syncthreads();
    int base = blockIdx.x * EPB;
#pragma unroll
    for (int it = 0; it < 8; ++it) {
        int e = base + it * 1024 + threadIdx.x;
        if (e < NE) atomicAdd(&h[dst[e] >> 8], 1);
    }
    __syncthreads();
    for (int i = threadIdx.x; i < NBUCK; i += 1024)
        if (h[i]) atomicAdd(&bcount[i], h[i]);
}

__global__ __launch_bounds__(512) void bucket_scan(const int* __restrict__ bcount, int* __restrict__ bbase,
                                                   int* __restrict__ bcursor) {
    __shared__ int s[512];
    int t = threadIdx.x;
    int v = (t < NBUCK) ? bcount[t] : 0;
    s[t] = v;
    __syncthreads();
    for (int off = 1; off < 512; off <<= 1) {
        int x = (t >= off) ? s[t - off] : 0;
        __syncthreads();
        s[t] += x;
        __syncthreads();
    }
    if (t < NBUCK) {
        int excl = s[t] - v;
        bbase[t] = excl;
        bcursor[t] = excl;
    }
    if (t == 0) bbase[NBUCK] = NE;
}

__global__ __launch_bounds__(1024) void pair_scatter(const int* __restrict__ src, const int* __restrict__ dst,
                                                     int* __restrict__ bcursor, int2* __restrict__ pairs) {
    __shared__ int h[NBUCK];
    __shared__ int base[NBUCK];
    __shared__ int cur[NBUCK];
    for (int i = threadIdx.x; i < NBUCK; i += 1024) h[i] = 0;
    __syncthreads();
    int e0 = blockIdx.x * EPB;
    int myd[8], mys[8];
#pragma unroll
    for (int it = 0; it < 8; ++it) {
        int e = e0 + it * 1024 + threadIdx.x;
        if (e < NE) {
            myd[it] = dst[e];
            mys[it] = src[e];
            atomicAdd(&h[myd[it] >> 8], 1);
        } else myd[it] = -1;
    }
    __syncthreads();
    for (int i = threadIdx.x; i < NBUCK; i += 1024) {
        base[i] = h[i] ? atomicAdd(&bcursor[i], h[i]) : 0;
        cur[i] = 0;
    }
    __syncthreads();
#pragma unroll
    for (int it = 0; it < 8; ++it) {
        if (myd[it] >= 0) {
            int b = myd[it] >> 8;
            int off = atomicAdd(&cur[b], 1);
            pairs[base[b] + off] = make_int2(myd[it], mys[it]);
        }
    }
}

__global__ __launch_bounds__(256) void bucket_build(const int2* __restrict__ pairs, const int* __restrict__ bbase,
                                                    int* __restrict__ rowptr, int* __restrict__ col) {
    __shared__ int deg[256];
    __shared__ int s[256];
    __shared__ int cur[256];
    int b = blockIdx.x, t = threadIdx.x;
    int pstart = bbase[b], pend = bbase[b + 1];
    deg[t] = 0;
    __syncthreads();
    for (int p = pstart + t; p < pend; p += 256)
        atomicAdd(&deg[pairs[p].x & 255], 1);
    __syncthreads();
    int v = deg[t];
    s[t] = v;
    __syncthreads();
    for (int off = 1; off < 256; off <<= 1) {
        int x = (t >= off) ? s[t - off] : 0;
        __syncthreads();
        s[t] += x;
        __syncthreads();
    }
    int excl = pstart + s[t] - v;
    int node = b * 256 + t;
    if (node < NN) rowptr[node] = excl;
    cur[t] = excl;
    __syncthreads();
    for (int p = pstart + t; p < pend; p += 256) {
        int2 pr = pairs[p];
        int pos = atomicAdd(&cur[pr.x & 255], 1);
        col[pos] = pr.y;
    }
    if (b == NBUCK - 1 && t == 0) rowptr[NN] = NE;
}

// ---------------- fp32 -> bf16 row conversion (for x) ----------------
__global__ __launch_bounds__(256) void f2bf(const float* __restrict__ X, unsigned short* __restrict__ O) {
    int i = blockIdx.x * 256 + threadIdx.x;   // 8-element group
    if (i >= NN * 16) return;
    const float4* X4 = (const float4*)X;
    float4 a = X4[2 * i], b = X4[2 * i + 1];
    ((ushort4*)O)[2 * i] = make_ushort4(f2bf_bits(a.x), f2bf_bits(a.y), f2bf_bits(a.z), f2bf_bits(a.w));
    ((ushort4*)O)[2 * i + 1] = make_ushort4(f2bf_bits(b.x), f2bf_bits(b.y), f2bf_bits(b.z), f2bf_bits(b.w));
}

// ---------------- aggregation with inline BN+ReLU on gathered bf16 rows ----------------
__global__ __launch_bounds__(256) void agg_bn(const unsigned short* __restrict__ hb, const int* __restrict__ rowptr,
                                              const int* __restrict__ col, float* __restrict__ z,
                                              const float* __restrict__ stats, const float* __restrict__ gamma,
                                              const float* __restrict__ beta, int dobn) {
    int node = blockIdx.x * 8 + (threadIdx.x >> 5);
    int l = threadIdx.x & 31;
    if (node >= NN) return;
    float4 sc = make_float4(1.f, 1.f, 1.f, 1.f);
    float4 sh = make_float4(0.f, 0.f, 0.f, 0.f);
    if (dobn) {
        const float4* S4 = (const float4*)stats;
        float4 cs4 = S4[l], cq4 = S4[32 + l];
        float4 g4 = ((const float4*)gamma)[l], be4 = ((const float4*)beta)[l];
        const float inv = 1.f / NN;
        float mu;
        mu = cs4.x * inv; sc.x = g4.x * rsqrtf(cq4.x * inv - mu * mu + BN_EPS); sh.x = be4.x - mu * sc.x;
        mu = cs4.y * inv; sc.y = g4.y * rsqrtf(cq4.y * inv - mu * mu + BN_EPS); sh.y = be4.y - mu * sc.y;
        mu = cs4.z * inv; sc.z = g4.z * rsqrtf(cq4.z * inv - mu * mu + BN_EPS); sh.z = be4.z - mu * sc.z;
        mu = cs4.w * inv; sc.w = g4.w * rsqrtf(cq4.w * inv - mu * mu + BN_EPS); sh.w = be4.w - mu * sc.w;
    }
    const ushort4* h4 = (const ushort4*)hb;
    auto xf = [&](ushort4 u) -> float4 {
        float4 v = bf4_to_f4(u);
        v.x = fmaf(v.x, sc.x, sh.x); v.y = fmaf(v.y, sc.y, sh.y);
        v.z = fmaf(v.z, sc.z, sh.z); v.w = fmaf(v.w, sc.w, sh.w);
        if (dobn) {
            v.x = fmaxf(v.x, 0.f); v.y = fmaxf(v.y, 0.f);
            v.z = fmaxf(v.z, 0.f); v.w = fmaxf(v.w, 0.f);
        }
        return v;
    };
    int s = rowptr[node], e = rowptr[node + 1];
    float4 acc = xf(h4[(size_t)node * 32 + l]);
    int j = s;
    for (; j + 3 < e; j += 4) {
        int c0 = col[j], c1 = col[j + 1], c2 = col[j + 2], c3 = col[j + 3];
        float4 v0 = xf(h4[(size_t)c0 * 32 + l]);
        float4 v1 = xf(h4[(size_t)c1 * 32 + l]);
        float4 v2 = xf(h4[(size_t)c2 * 32 + l]);
        float4 v3 = xf(h4[(size_t)c3 * 32 + l]);
        acc.x += v0.x + v1.x + v2.x + v3.x;
        acc.y += v0.y + v1.y + v2.y + v3.y;
        acc.z += v0.z + v1.z + v2.z + v3.z;
        acc.w += v0.w + v1.w + v2.w + v3.w;
    }
    for (; j < e; ++j) {
        float4 v = xf(h4[(size_t)col[j] * 32 + l]);
        acc.x += v.x; acc.y += v.y; acc.z += v.z; acc.w += v.w;
    }
    ((float4*)z)[(size_t)node * 32 + l] = acc;
}

// ---------------- W pre-pack: fp32 [128][128] -> single bf16 plane in MFMA B-fragment order ----
// Wp[((t*4 + s)*64 + lane)*8 + j]; lane holds B[k = s*32 + (lane>>4)*8 + j][n = t*16 + (lane&15)].
__global__ __launch_bounds__(256) void pack_w(const float* __restrict__ W, unsigned short* __restrict__ Wp,
                                              int which) {
    int t = blockIdx.x;
    int layer = blockIdx.y;
    int s = threadIdx.x >> 6;
    int lane = threadIdx.x & 63;
    int n = t * 16 + (lane & 15);
    int k0 = s * 32 + (lane >> 4) * 8;
    const float* Ws = W + (size_t)layer * HID * HID;
    unsigned short* dst = Wp + (size_t)(2 * layer + which) * 16384;
    size_t base = (size_t)((t * 4 + s) * 64 + lane) * 8;
#pragma unroll
    for (int j = 0; j < 8; ++j) dst[base + j] = f2bf_bits(Ws[(k0 + j) * 128 + n]);
}

__device__ inline void split8(const float* p, bool ok, short8& hi, short8& lo) {
    float v[8];
    if (ok) {
        float4 a = *(const float4*)p;
        float4 b = *(const float4*)(p + 4);
        v[0] = a.x; v[1] = a.y; v[2] = a.z; v[3] = a.w;
        v[4] = b.x; v[5] = b.y; v[6] = b.z; v[7] = b.w;
    } else {
#pragma unroll
        for (int j = 0; j < 8; ++j) v[j] = 0.f;
    }
#pragma unroll
    for (int j = 0; j < 8; ++j) {
        unsigned short h = f2bf_bits(v[j]);
        float hf = __uint_as_float((unsigned)h << 16);
        hi[j] = (short)h;
        lo[j] = (short)f2bf_bits(v[j] - hf);
    }
}

// ---------------- fused per-layer MLP: z2 = relu(z@W1b+b1)@W2b + b2, bf16 out + stats ----------------
// 128 rows/block, 512 threads (8 waves), wave w owns rows w*16..w*16+15.
// LDS: W1b 32K + W2b 32K + z1 hi/lo (pitch 136) 68K + cs 1K = 136 KB (gfx950: 160 KB addressable).
#define Z1P 136
__global__ __launch_bounds__(512, 1) void mlp_fused(const float* __restrict__ A,
        const unsigned short* __restrict__ W1p, const float* __restrict__ b1v,
        const unsigned short* __restrict__ W2p, const float* __restrict__ b2v,
        unsigned short* __restrict__ Zb, float* __restrict__ stats) {
    __shared__ unsigned short W1s[16384];
    __shared__ unsigned short W2s[16384];
    __shared__ unsigned short Z1h[128 * Z1P];
    __shared__ unsigned short Z1l[128 * Z1P];
    __shared__ float cs[256];
    int tid = threadIdx.x;
    {
        const uint4* g1 = (const uint4*)W1p;
        const uint4* g2 = (const uint4*)W2p;
        uint4* s1 = (uint4*)W1s;
        uint4* s2 = (uint4*)W2s;
#pragma unroll
        for (int it = 0; it < 4; ++it) {
            s1[tid + it * 512] = g1[tid + it * 512];
            s2[tid + it * 512] = g2[tid + it * 512];
        }
    }
    if (tid < 256) cs[tid] = 0.f;
    __syncthreads();

    int lane = tid & 63, wave = tid >> 6;
    int m = lane & 15, quad = lane >> 4;
    int row0 = blockIdx.x * 128;
    int r = row0 + wave * 16 + m;
    bool ok = r < NN;
    const float* Ar = A + (size_t)r * HID;

    floatx4 acc1[8];
#pragma unroll
    for (int t = 0; t < 8; ++t) acc1[t] = (floatx4){0.f, 0.f, 0.f, 0.f};
#pragma unroll
    for (int s = 0; s < 4; ++s) {
        short8 ah, al;
        split8(Ar + s * 32 + quad * 8, ok, ah, al);
#pragma unroll
        for (int t = 0; t < 8; ++t) {
            short8 bh = *(short8*)&W1s[((t * 4 + s) * 64 + lane) * 8];
            acc1[t] = __builtin_amdgcn_mfma_f32_16x16x32_bf16(ah, bh, acc1[t], 0, 0, 0);
            acc1[t] = __builtin_amdgcn_mfma_f32_16x16x32_bf16(al, bh, acc1[t], 0, 0, 0);
        }
    }
    // relu(acc1 + b1) -> Z1 hi/lo (C-layout -> row-major LDS)
#pragma unroll
    for (int t = 0; t < 8; ++t) {
        int colc = t * 16 + m;
        float bv = b1v[colc];
#pragma unroll
        for (int rr = 0; rr < 4; ++rr) {
            int lrow = wave * 16 + quad * 4 + rr;
            float o = fmaxf(acc1[t][rr] + bv, 0.f);
            unsigned short hi = f2bf_bits(o);
            float hf = __uint_as_float((unsigned)hi << 16);
            Z1h[lrow * Z1P + colc] = hi;
            Z1l[lrow * Z1P + colc] = f2bf_bits(o - hf);
        }
    }
    __syncthreads();

    floatx4 acc2[8];
#pragma unroll
    for (int t = 0; t < 8; ++t) acc2[t] = (floatx4){0.f, 0.f, 0.f, 0.f};
#pragma unroll
    for (int s = 0; s < 4; ++s) {
        short8 ah = *(short8*)&Z1h[(wave * 16 + m) * Z1P + s * 32 + quad * 8];
        short8 al = *(short8*)&Z1l[(wave * 16 + m) * Z1P + s * 32 + quad * 8];
#pragma unroll
        for (int t = 0; t < 8; ++t) {
            short8 bh = *(short8*)&W2s[((t * 4 + s) * 64 + lane) * 8];
            acc2[t] = __builtin_amdgcn_mfma_f32_16x16x32_bf16(ah, bh, acc2[t], 0, 0, 0);
            acc2[t] = __builtin_amdgcn_mfma_f32_16x16x32_bf16(al, bh, acc2[t], 0, 0, 0);
        }
    }
    // epilogue: z2 bf16 store + column stats
#pragma unroll
    for (int t = 0; t < 8; ++t) {
        int colc = t * 16 + m;
        float bv = b2v[colc];
        float csum = 0.f, csq = 0.f;
#pragma unroll
        for (int rr = 0; rr < 4; ++rr) {
            int grow = row0 + wave * 16 + quad * 4 + rr;
            if (grow < NN) {
                float o = acc2[t][rr] + bv;
                Zb[(size_t)grow * HID + colc] = f2bf_bits(o);
                csum += o; csq += o * o;
            }
        }
        csum += __shfl_xor(csum, 16); csum += __shfl_xor(csum, 32);
        csq  += __shfl_xor(csq, 16);  csq  += __shfl_xor(csq, 32);
        if (quad == 0) {
            atomicAdd(&cs[colc], csum);
            atomicAdd(&cs[128 + colc], csq);
        }
    }
    __syncthreads();
    if (tid < 256) atomicAdd(&stats[tid], cs[tid]);
}

// ---------------- final BN+ReLU: bf16 z2 -> fp32 node embeddings ----------------
__global__ __launch_bounds__(256) void bn_relu_out(const unsigned short* __restrict__ Zb,
                                                   const float* __restrict__ stats,
                                                   const float* __restrict__ gamma, const float* __restrict__ beta,
                                                   float* __restrict__ out) {
    int i = blockIdx.x * 256 + threadIdx.x;   // float4 group
    if (i >= NN * 32) return;
    int c4 = i & 31;
    const float4* S4 = (const float4*)stats;
    float4 cs4 = S4[c4], cq4 = S4[32 + c4];
    float4 g4 = ((const float4*)gamma)[c4], be4 = ((const float4*)beta)[c4];
    const float inv = 1.f / NN;
    float4 sc, sh;
    float mu;
    mu = cs4.x * inv; sc.x = g4.x * rsqrtf(cq4.x * inv - mu * mu + BN_EPS); sh.x = be4.x - mu * sc.x;
    mu = cs4.y * inv; sc.y = g4.y * rsqrtf(cq4.y * inv - mu * mu + BN_EPS); sh.y = be4.y - mu * sc.y;
    mu = cs4.z * inv; sc.z = g4.z * rsqrtf(cq4.z * inv - mu * mu + BN_EPS); sh.z = be4.z - mu * sc.z;
    mu = cs4.w * inv; sc.w = g4.w * rsqrtf(cq4.w * inv - mu * mu + BN_EPS); sh.w = be4.w - mu * sc.w;
    float4 v = bf4_to_f4(((const ushort4*)Zb)[i]);
    v.x = fmaxf(fmaf(v.x, sc.x, sh.x), 0.f);
    v.y = fmaxf(fmaf(v.y, sc.y, sh.y), 0.f);
    v.z = fmaxf(fmaf(v.z, sc.z, sh.z), 0.f);
    v.w = fmaxf(fmaf(v.w, sc.w, sh.w), 0.f);
    ((float4*)out)[i] = v;
}

// ---------------- pooling ----------------
__global__ void find_starts(const int* __restrict__ batch, int* __restrict__ starts) {
    int g = threadIdx.x;
    if (g > NG) return;
    int lo = 0, hi = NN;
    while (lo < hi) {
        int mid = (lo + hi) >> 1;
        if (batch[mid] < g) lo = mid + 1; else hi = mid;
    }
    starts[g] = lo;
}

__global__ __launch_bounds__(128) void pool_partial(const float* __restrict__ H, const int* __restrict__ starts,
                                                    float* __restrict__ gsum) {
    int g = blockIdx.x, slice = blockIdx.y, t = threadIdx.x;
    int s = starts[g], e = starts[g + 1];
    int len = e - s;
    if (len <= 0) return;
    int chunk = (len + 7) >> 3;
    int a = s + slice * chunk;
    int b = min(e, a + chunk);
    if (a >= b) return;
    float acc = 0.f;
    for (int r = a; r < b; ++r) acc += H[(size_t)r * HID + t];
    atomicAdd(&gsum[g * HID + t], acc);
}

__global__ void pool_final(const float* __restrict__ gsum, const int* __restrict__ starts, float* __restrict__ outG) {
    int g = blockIdx.x, t = threadIdx.x;
    float cnt = (float)(starts[g + 1] - starts[g]);
    cnt = fmaxf(cnt, 1.f);
    outG[g * HID + t] = gsum[g * HID + t] / cnt;
}

extern "C" void kernel_launch(void* const* d_in, const int* in_sizes, int n_in,
                              void* d_out, int out_size, void* d_ws, size_t ws_size,
                              hipStream_t stream) {
    const float* x = (const float*)d_in[0];
    const int* ei = (const int*)d_in[1];
    const int* batch = (const int*)d_in[2];
    const float* W1 = (const float*)d_in[3];
    const float* b1 = (const float*)d_in[4];
    const float* W2 = (const float*)d_in[5];
    const float* b2 = (const float*)d_in[6];
    const float* gamma = (const float*)d_in[7];
    const float* beta = (const float*)d_in[8];
    float* out = (float*)d_out;
    float* outG = out + (size_t)NN * HID;

    // workspace layout
    float* S0 = (float*)d_ws;                                   // 12.8M floats (fp32 z)
    unsigned short* B0 = (unsigned short*)(S0 + (size_t)NN * HID); // 12.8M ushorts (bf16 node buf)
    int* col = (int*)(B0 + (size_t)NN * HID);                   // NE
    int* rowptr = col + NE;                                     // 100004 reserved
    int* bcount = rowptr + 100004;                              // 512
    int* bbase = bcount + 512;                                  // 512
    int* bcursor = bbase + 512;                                 // 512
    int* starts = bcursor + 512;                                // 80 reserved
    float* stats = (float*)(starts + 80);                       // 256 (sum | sumsq)
    float* gsum = stats + 256;                                  // 8192
    unsigned short* Wp = (unsigned short*)(gsum + 8192);        // 6 x 16384 ushorts
    int2* pairs = (int2*)B0;                                    // aliases B0 (CSR build only, before f2bf)

    const int* srcv = ei;
    const int* dstv = ei + NE;

    // bucketed CSR build
    hipMemsetAsync(bcount, 0, 512 * sizeof(int), stream);
    bucket_hist<<<NSB, 1024, 0, stream>>>(dstv, bcount);
    bucket_scan<<<1, 512, 0, stream>>>(bcount, bbase, bcursor);
    pair_scatter<<<NSB, 1024, 0, stream>>>(srcv, dstv, bcursor, pairs);
    bucket_build<<<NBUCK, 256, 0, stream>>>(pairs, bbase, rowptr, col);

    // pack weights (single bf16 plane, fragment order); convert x to bf16
    pack_w<<<dim3(8, 3), 256, 0, stream>>>(W1, Wp, 0);
    pack_w<<<dim3(8, 3), 256, 0, stream>>>(W2, Wp, 1);
    f2bf<<<NN * 16 / 256, 256, 0, stream>>>(x, B0);

    const int nmlp = (NN + 127) / 128;
    for (int l = 0; l < 3; ++l) {
        const float* g = gamma + (l ? (l - 1) * HID : 0);
        const float* be = beta + (l ? (l - 1) * HID : 0);
        agg_bn<<<NN / 8, 256, 0, stream>>>(B0, rowptr, col, S0, stats, g, be, l > 0 ? 1 : 0);
        hipMemsetAsync(stats, 0, 256 * sizeof(float), stream);
        mlp_fused<<<nmlp, 512, 0, stream>>>(S0, Wp + (size_t)(2 * l) * 16384, b1 + l * HID,
                                            Wp + (size_t)(2 * l + 1) * 16384, b2 + l * HID, B0, stats);
    }
    bn_relu_out<<<NN * 32 / 256, 256, 0, stream>>>(B0, stats, gamma + 2 * HID, beta + 2 * HID, out);

    find_starts<<<1, 128, 0, stream>>>(batch, starts);
    hipMemsetAsync(gsum, 0, NG * HID * sizeof(float), stream);
    pool_partial<<<dim3(NG, 8), 128, 0, stream>>>(out, starts, gsum);
    pool_final<<<NG, 128, 0, stream>>>(gsum, starts, outG);
}

// Round 6
// 692.319 us; speedup vs baseline: 1.9306x; 1.0075x over previous
//
#include <hip/hip_runtime.h>
#include <hip/hip_bf16.h>

#define NN 100000
#define NE 1600000
#define HID 128
#define NG 64
#define BN_EPS 1e-5f
#define NBUCK 391      // buckets of 256 nodes (dst>>8)
#define EPB 8192       // edges per pair_scatter block
#define NSB 196        // ceil(NE/EPB)

typedef __attribute__((ext_vector_type(8))) short short8;
typedef __attribute__((ext_vector_type(4))) float floatx4;

__device__ inline unsigned short f2bf_bits(float v) {
    __hip_bfloat16 h = __float2bfloat16(v);
    unsigned short u;
    __builtin_memcpy(&u, &h, 2);
    return u;
}
__device__ inline float4 bf4_to_f4(ushort4 u) {
    float4 f;
    f.x = __uint_as_float((unsigned)u.x << 16);
    f.y = __uint_as_float((unsigned)u.y << 16);
    f.z = __uint_as_float((unsigned)u.z << 16);
    f.w = __uint_as_float((unsigned)u.w << 16);
    return f;
}

// ---------------- bucketed CSR build ----------------
__global__ __launch_bounds__(1024) void bucket_hist(const int* __restrict__ dst, int* __restrict__ bcount) {
    __shared__ int h[NBUCK];
    for (int i = threadIdx.x; i < NBUCK; i += 1024) h[i] = 0;
    __syncthreads();
    int base = blockIdx.x * EPB;
#pragma unroll
    for (int it = 0; it < 8; ++it) {
        int e = base + it * 1024 + threadIdx.x;
        if (e < NE) atomicAdd(&h[dst[e] >> 8], 1);
    }
    __syncthreads();
    for (int i = threadIdx.x; i < NBUCK; i += 1024)
        if (h[i]) atomicAdd(&bcount[i], h[i]);
}

__global__ __launch_bounds__(512) void bucket_scan(const int* __restrict__ bcount, int* __restrict__ bbase,
                                                   int* __restrict__ bcursor) {
    __shared__ int s[512];
    int t = threadIdx.x;
    int v = (t < NBUCK) ? bcount[t] : 0;
    s[t] = v;
    __syncthreads();
    for (int off = 1; off < 512; off <<= 1) {
        int x = (t >= off) ? s[t - off] : 0;
        __syncthreads();
        s[t] += x;
        __syncthreads();
    }
    if (t < NBUCK) {
        int excl = s[t] - v;
        bbase[t] = excl;
        bcursor[t] = excl;
    }
    if (t == 0) bbase[NBUCK] = NE;
}

__global__ __launch_bounds__(1024) void pair_scatter(const int* __restrict__ src, const int* __restrict__ dst,
                                                     int* __restrict__ bcursor, int2* __restrict__ pairs) {
    __shared__ int h[NBUCK];
    __shared__ int base[NBUCK];
    __shared__ int cur[NBUCK];
    for (int i = threadIdx.x; i < NBUCK; i += 1024) h[i] = 0;
    __syncthreads();
    int e0 = blockIdx.x * EPB;
    int myd[8], mys[8];
#pragma unroll
    for (int it = 0; it < 8; ++it) {
        int e = e0 + it * 1024 + threadIdx.x;
        if (e < NE) {
            myd[it] = dst[e];
            mys[it] = src[e];
            atomicAdd(&h[myd[it] >> 8], 1);
        } else myd[it] = -1;
    }
    __syncthreads();
    for (int i = threadIdx.x; i < NBUCK; i += 1024) {
        base[i] = h[i] ? atomicAdd(&bcursor[i], h[i]) : 0;
        cur[i] = 0;
    }
    __syncthreads();
#pragma unroll
    for (int it = 0; it < 8; ++it) {
        if (myd[it] >= 0) {
            int b = myd[it] >> 8;
            int off = atomicAdd(&cur[b], 1);
            pairs[base[b] + off] = make_int2(myd[it], mys[it]);
        }
    }
}

__global__ __launch_bounds__(256) void bucket_build(const int2* __restrict__ pairs, const int* __restrict__ bbase,
                                                    int* __restrict__ rowptr, int* __restrict__ col) {
    __shared__ int deg[256];
    __shared__ int s[256];
    __shared__ int cur[256];
    int b = blockIdx.x, t = threadIdx.x;
    int pstart = bbase[b], pend = bbase[b + 1];
    deg[t] = 0;
    __syncthreads();
    for (int p = pstart + t; p < pend; p += 256)
        atomicAdd(&deg[pairs[p].x & 255], 1);
    __syncthreads();
    int v = deg[t];
    s[t] = v;
    __syncthreads();
    for (int off = 1; off < 256; off <<= 1) {
        int x = (t >= off) ? s[t - off] : 0;
        __syncthreads();
        s[t] += x;
        __syncthreads();
    }
    int excl = pstart + s[t] - v;
    int node = b * 256 + t;
    if (node < NN) rowptr[node] = excl;
    cur[t] = excl;
    __syncthreads();
    for (int p = pstart + t; p < pend; p += 256) {
        int2 pr = pairs[p];
        int pos = atomicAdd(&cur[pr.x & 255], 1);
        col[pos] = pr.y;
    }
    if (b == NBUCK - 1 && t == 0) rowptr[NN] = NE;
}

// ---------------- fp32 -> bf16 row conversion (for x) ----------------
__global__ __launch_bounds__(256) void f2bf(const float* __restrict__ X, unsigned short* __restrict__ O) {
    int i = blockIdx.x * 256 + threadIdx.x;   // 8-element group
    if (i >= NN * 16) return;
    const float4* X4 = (const float4*)X;
    float4 a = X4[2 * i], b = X4[2 * i + 1];
    ((ushort4*)O)[2 * i] = make_ushort4(f2bf_bits(a.x), f2bf_bits(a.y), f2bf_bits(a.z), f2bf_bits(a.w));
    ((ushort4*)O)[2 * i + 1] = make_ushort4(f2bf_bits(b.x), f2bf_bits(b.y), f2bf_bits(b.z), f2bf_bits(b.w));
}

// ---------------- plain aggregation over bf16 rows ----------------
__global__ __launch_bounds__(256) void agg_bf(const unsigned short* __restrict__ hb, const int* __restrict__ rowptr,
                                              const int* __restrict__ col, float* __restrict__ z) {
    int node = blockIdx.x * 8 + (threadIdx.x >> 5);
    int l = threadIdx.x & 31;
    if (node >= NN) return;
    const ushort4* h4 = (const ushort4*)hb;
    int s = rowptr[node], e = rowptr[node + 1];
    float4 acc = bf4_to_f4(h4[(size_t)node * 32 + l]);
    int j = s;
    for (; j + 3 < e; j += 4) {
        int c0 = col[j], c1 = col[j + 1], c2 = col[j + 2], c3 = col[j + 3];
        float4 v0 = bf4_to_f4(h4[(size_t)c0 * 32 + l]);
        float4 v1 = bf4_to_f4(h4[(size_t)c1 * 32 + l]);
        float4 v2 = bf4_to_f4(h4[(size_t)c2 * 32 + l]);
        float4 v3 = bf4_to_f4(h4[(size_t)c3 * 32 + l]);
        acc.x += v0.x + v1.x + v2.x + v3.x;
        acc.y += v0.y + v1.y + v2.y + v3.y;
        acc.z += v0.z + v1.z + v2.z + v3.z;
        acc.w += v0.w + v1.w + v2.w + v3.w;
    }
    for (; j < e; ++j) {
        float4 v = bf4_to_f4(h4[(size_t)col[j] * 32 + l]);
        acc.x += v.x; acc.y += v.y; acc.z += v.z; acc.w += v.w;
    }
    ((float4*)z)[(size_t)node * 32 + l] = acc;
}

// ---------------- W pre-pack: fp32 [128][128] -> single bf16 plane in MFMA B-fragment order ----
// Wp[((t*4 + s)*64 + lane)*8 + j]; lane holds B[k = s*32 + (lane>>4)*8 + j][n = t*16 + (lane&15)].
__global__ __launch_bounds__(256) void pack_w(const float* __restrict__ W, unsigned short* __restrict__ Wp,
                                              int which) {
    int t = blockIdx.x;
    int layer = blockIdx.y;
    int s = threadIdx.x >> 6;
    int lane = threadIdx.x & 63;
    int n = t * 16 + (lane & 15);
    int k0 = s * 32 + (lane >> 4) * 8;
    const float* Ws = W + (size_t)layer * HID * HID;
    unsigned short* dst = Wp + (size_t)(2 * layer + which) * 16384;
    size_t base = (size_t)((t * 4 + s) * 64 + lane) * 8;
#pragma unroll
    for (int j = 0; j < 8; ++j) dst[base + j] = f2bf_bits(Ws[(k0 + j) * 128 + n]);
}

__device__ inline void split8(const float* p, bool ok, short8& hi, short8& lo) {
    float v[8];
    if (ok) {
        float4 a = *(const float4*)p;
        float4 b = *(const float4*)(p + 4);
        v[0] = a.x; v[1] = a.y; v[2] = a.z; v[3] = a.w;
        v[4] = b.x; v[5] = b.y; v[6] = b.z; v[7] = b.w;
    } else {
#pragma unroll
        for (int j = 0; j < 8; ++j) v[j] = 0.f;
    }
#pragma unroll
    for (int j = 0; j < 8; ++j) {
        unsigned short h = f2bf_bits(v[j]);
        float hf = __uint_as_float((unsigned)h << 16);
        hi[j] = (short)h;
        lo[j] = (short)f2bf_bits(v[j] - hf);
    }
}

// ---------------- fused per-layer MLP v2: W direct-from-global, small LDS, 4 blocks/CU ----------------
// 64 rows/block, 256 threads (4 waves), wave w owns rows w*16..w*16+15.
// LDS: Z1 hi/lo (pitch 136) 2x17.4 KB + cs 1 KB ~= 36 KB.
#define Z1P 136
__global__ __launch_bounds__(256) void mlp_v2(const float* __restrict__ A,
        const unsigned short* __restrict__ W1p, const float* __restrict__ b1v,
        const unsigned short* __restrict__ W2p, const float* __restrict__ b2v,
        unsigned short* __restrict__ Zb, float* __restrict__ stats) {
    __shared__ unsigned short Z1h[64 * Z1P];
    __shared__ unsigned short Z1l[64 * Z1P];
    __shared__ float cs[256];
    int tid = threadIdx.x;
    cs[tid] = 0.f;

    int lane = tid & 63, wave = tid >> 6;
    int m = lane & 15, quad = lane >> 4;
    int row0 = blockIdx.x * 64;
    int r = row0 + wave * 16 + m;
    bool ok = r < NN;
    const float* Ar = A + (size_t)r * HID;
    const short8* W1f = (const short8*)W1p;   // fragment f = (t*4+s)*64+lane
    const short8* W2f = (const short8*)W2p;

    floatx4 acc1[8];
#pragma unroll
    for (int t = 0; t < 8; ++t) acc1[t] = (floatx4){0.f, 0.f, 0.f, 0.f};
#pragma unroll
    for (int s = 0; s < 4; ++s) {
        short8 ah, al;
        split8(Ar + s * 32 + quad * 8, ok, ah, al);
#pragma unroll
        for (int t = 0; t < 8; ++t) {
            short8 bh = W1f[(t * 4 + s) * 64 + lane];
            acc1[t] = __builtin_amdgcn_mfma_f32_16x16x32_bf16(ah, bh, acc1[t], 0, 0, 0);
            acc1[t] = __builtin_amdgcn_mfma_f32_16x16x32_bf16(al, bh, acc1[t], 0, 0, 0);
        }
    }
    // relu(acc1 + b1) -> Z1 hi/lo (C-layout: row=wave*16+quad*4+rr, col=t*16+m)
#pragma unroll
    for (int t = 0; t < 8; ++t) {
        int colc = t * 16 + m;
        float bv = b1v[colc];
#pragma unroll
        for (int rr = 0; rr < 4; ++rr) {
            int lrow = wave * 16 + quad * 4 + rr;
            float o = fmaxf(acc1[t][rr] + bv, 0.f);
            unsigned short hi = f2bf_bits(o);
            float hf = __uint_as_float((unsigned)hi << 16);
            Z1h[lrow * Z1P + colc] = hi;
            Z1l[lrow * Z1P + colc] = f2bf_bits(o - hf);
        }
    }
    __syncthreads();

    floatx4 acc2[8];
#pragma unroll
    for (int t = 0; t < 8; ++t) acc2[t] = (floatx4){0.f, 0.f, 0.f, 0.f};
#pragma unroll
    for (int s = 0; s < 4; ++s) {
        short8 ah = *(short8*)&Z1h[(wave * 16 + m) * Z1P + s * 32 + quad * 8];
        short8 al = *(short8*)&Z1l[(wave * 16 + m) * Z1P + s * 32 + quad * 8];
#pragma unroll
        for (int t = 0; t < 8; ++t) {
            short8 bh = W2f[(t * 4 + s) * 64 + lane];
            acc2[t] = __builtin_amdgcn_mfma_f32_16x16x32_bf16(ah, bh, acc2[t], 0, 0, 0);
            acc2[t] = __builtin_amdgcn_mfma_f32_16x16x32_bf16(al, bh, acc2[t], 0, 0, 0);
        }
    }
    // epilogue: z2 bf16 store + column stats
#pragma unroll
    for (int t = 0; t < 8; ++t) {
        int colc = t * 16 + m;
        float bv = b2v[colc];
        float csum = 0.f, csq = 0.f;
#pragma unroll
        for (int rr = 0; rr < 4; ++rr) {
            int grow = row0 + wave * 16 + quad * 4 + rr;
            if (grow < NN) {
                float o = acc2[t][rr] + bv;
                Zb[(size_t)grow * HID + colc] = f2bf_bits(o);
                csum += o; csq += o * o;
            }
        }
        csum += __shfl_xor(csum, 16); csum += __shfl_xor(csum, 32);
        csq  += __shfl_xor(csq, 16);  csq  += __shfl_xor(csq, 32);
        if (quad == 0) {
            atomicAdd(&cs[colc], csum);
            atomicAdd(&cs[128 + colc], csq);
        }
    }
    __syncthreads();
    atomicAdd(&stats[tid], cs[tid]);
}

// ---------------- BN+ReLU in-place on bf16 z2 ----------------
__global__ __launch_bounds__(256) void bn_relu_bf(unsigned short* __restrict__ Zb,
                                                  const float* __restrict__ stats,
                                                  const float* __restrict__ gamma, const float* __restrict__ beta) {
    int i = blockIdx.x * 256 + threadIdx.x;   // 8-col group
    if (i >= NN * 16) return;
    int g = i & 15;
    const float4* S4 = (const float4*)stats;
    const float inv = 1.f / NN;
    float4 sc0, sc1, sh0, sh1;
    {
        float4 cs4 = S4[g * 2], cq4 = S4[32 + g * 2];
        float4 g4 = ((const float4*)gamma)[g * 2], be4 = ((const float4*)beta)[g * 2];
        float mu;
        mu = cs4.x * inv; sc0.x = g4.x * rsqrtf(cq4.x * inv - mu * mu + BN_EPS); sh0.x = be4.x - mu * sc0.x;
        mu = cs4.y * inv; sc0.y = g4.y * rsqrtf(cq4.y * inv - mu * mu + BN_EPS); sh0.y = be4.y - mu * sc0.y;
        mu = cs4.z * inv; sc0.z = g4.z * rsqrtf(cq4.z * inv - mu * mu + BN_EPS); sh0.z = be4.z - mu * sc0.z;
        mu = cs4.w * inv; sc0.w = g4.w * rsqrtf(cq4.w * inv - mu * mu + BN_EPS); sh0.w = be4.w - mu * sc0.w;
        cs4 = S4[g * 2 + 1]; cq4 = S4[32 + g * 2 + 1];
        g4 = ((const float4*)gamma)[g * 2 + 1]; be4 = ((const float4*)beta)[g * 2 + 1];
        mu = cs4.x * inv; sc1.x = g4.x * rsqrtf(cq4.x * inv - mu * mu + BN_EPS); sh1.x = be4.x - mu * sc1.x;
        mu = cs4.y * inv; sc1.y = g4.y * rsqrtf(cq4.y * inv - mu * mu + BN_EPS); sh1.y = be4.y - mu * sc1.y;
        mu = cs4.z * inv; sc1.z = g4.z * rsqrtf(cq4.z * inv - mu * mu + BN_EPS); sh1.z = be4.z - mu * sc1.z;
        mu = cs4.w * inv; sc1.w = g4.w * rsqrtf(cq4.w * inv - mu * mu + BN_EPS); sh1.w = be4.w - mu * sc1.w;
    }
    ushort4 u0 = ((ushort4*)Zb)[2 * i], u1 = ((ushort4*)Zb)[2 * i + 1];
    float4 a = bf4_to_f4(u0), b = bf4_to_f4(u1);
    a.x = fmaxf(fmaf(a.x, sc0.x, sh0.x), 0.f); a.y = fmaxf(fmaf(a.y, sc0.y, sh0.y), 0.f);
    a.z = fmaxf(fmaf(a.z, sc0.z, sh0.z), 0.f); a.w = fmaxf(fmaf(a.w, sc0.w, sh0.w), 0.f);
    b.x = fmaxf(fmaf(b.x, sc1.x, sh1.x), 0.f); b.y = fmaxf(fmaf(b.y, sc1.y, sh1.y), 0.f);
    b.z = fmaxf(fmaf(b.z, sc1.z, sh1.z), 0.f); b.w = fmaxf(fmaf(b.w, sc1.w, sh1.w), 0.f);
    ((ushort4*)Zb)[2 * i] = make_ushort4(f2bf_bits(a.x), f2bf_bits(a.y), f2bf_bits(a.z), f2bf_bits(a.w));
    ((ushort4*)Zb)[2 * i + 1] = make_ushort4(f2bf_bits(b.x), f2bf_bits(b.y), f2bf_bits(b.z), f2bf_bits(b.w));
}

// ---------------- final BN+ReLU: bf16 z2 -> fp32 node embeddings ----------------
__global__ __launch_bounds__(256) void bn_relu_out(const unsigned short* __restrict__ Zb,
                                                   const float* __restrict__ stats,
                                                   const float* __restrict__ gamma, const float* __restrict__ beta,
                                                   float* __restrict__ out) {
    int i = blockIdx.x * 256 + threadIdx.x;   // float4 group
    if (i >= NN * 32) return;
    int c4 = i & 31;
    const float4* S4 = (const float4*)stats;
    float4 cs4 = S4[c4], cq4 = S4[32 + c4];
    float4 g4 = ((const float4*)gamma)[c4], be4 = ((const float4*)beta)[c4];
    const float inv = 1.f / NN;
    float4 sc, sh;
    float mu;
    mu = cs4.x * inv; sc.x = g4.x * rsqrtf(cq4.x * inv - mu * mu + BN_EPS); sh.x = be4.x - mu * sc.x;
    mu = cs4.y * inv; sc.y = g4.y * rsqrtf(cq4.y * inv - mu * mu + BN_EPS); sh.y = be4.y - mu * sc.y;
    mu = cs4.z * inv; sc.z = g4.z * rsqrtf(cq4.z * inv - mu * mu + BN_EPS); sh.z = be4.z - mu * sc.z;
    mu = cs4.w * inv; sc.w = g4.w * rsqrtf(cq4.w * inv - mu * mu + BN_EPS); sh.w = be4.w - mu * sc.w;
    float4 v = bf4_to_f4(((const ushort4*)Zb)[i]);
    v.x = fmaxf(fmaf(v.x, sc.x, sh.x), 0.f);
    v.y = fmaxf(fmaf(v.y, sc.y, sh.y), 0.f);
    v.z = fmaxf(fmaf(v.z, sc.z, sh.z), 0.f);
    v.w = fmaxf(fmaf(v.w, sc.w, sh.w), 0.f);
    ((float4*)out)[i] = v;
}

// ---------------- pooling ----------------
__global__ void find_starts(const int* __restrict__ batch, int* __restrict__ starts) {
    int g = threadIdx.x;
    if (g > NG) return;
    int lo = 0, hi = NN;
    while (lo < hi) {
        int mid = (lo + hi) >> 1;
        if (batch[mid] < g) lo = mid + 1; else hi = mid;
    }
    starts[g] = lo;
}

__global__ __launch_bounds__(128) void pool_partial(const float* __restrict__ H, const int* __restrict__ starts,
                                                    float* __restrict__ gsum) {
    int g = blockIdx.x, slice = blockIdx.y, t = threadIdx.x;
    int s = starts[g], e = starts[g + 1];
    int len = e - s;
    if (len <= 0) return;
    int chunk = (len + 7) >> 3;
    int a = s + slice * chunk;
    int b = min(e, a + chunk);
    if (a >= b) return;
    float acc = 0.f;
    for (int r = a; r < b; ++r) acc += H[(size_t)r * HID + t];
    atomicAdd(&gsum[g * HID + t], acc);
}

__global__ void pool_final(const float* __restrict__ gsum, const int* __restrict__ starts, float* __restrict__ outG) {
    int g = blockIdx.x, t = threadIdx.x;
    float cnt = (float)(starts[g + 1] - starts[g]);
    cnt = fmaxf(cnt, 1.f);
    outG[g * HID + t] = gsum[g * HID + t] / cnt;
}

extern "C" void kernel_launch(void* const* d_in, const int* in_sizes, int n_in,
                              void* d_out, int out_size, void* d_ws, size_t ws_size,
                              hipStream_t stream) {
    const float* x = (const float*)d_in[0];
    const int* ei = (const int*)d_in[1];
    const int* batch = (const int*)d_in[2];
    const float* W1 = (const float*)d_in[3];
    const float* b1 = (const float*)d_in[4];
    const float* W2 = (const float*)d_in[5];
    const float* b2 = (const float*)d_in[6];
    const float* gamma = (const float*)d_in[7];
    const float* beta = (const float*)d_in[8];
    float* out = (float*)d_out;
    float* outG = out + (size_t)NN * HID;

    // workspace layout
    float* S0 = (float*)d_ws;                                      // 12.8M floats (fp32 z)
    unsigned short* B0 = (unsigned short*)(S0 + (size_t)NN * HID); // 12.8M ushorts (bf16 node buf)
    int* col = (int*)(B0 + (size_t)NN * HID);                      // NE
    int* rowptr = col + NE;                                        // 100004 reserved
    int* starts = rowptr + 100004;                                 // 80 reserved
    int* bbase = starts + 80;                                      // 512
    int* bcursor = bbase + 512;                                    // 512
    // zero region: bcount(512 int) + stats 3x256 + gsum 8192 floats, contiguous
    int* bcount = bcursor + 512;                                   // 512
    float* stats = (float*)(bcount + 512);                         // 3 x 256
    float* gsum = stats + 768;                                     // 8192
    unsigned short* Wp = (unsigned short*)(gsum + 8192);           // 6 x 16384 ushorts
    int2* pairs = (int2*)B0;                                       // aliases B0 (CSR build only)

    const int* srcv = ei;
    const int* dstv = ei + NE;

    // single zeroing memset for bcount + stats + gsum
    hipMemsetAsync(bcount, 0, (512 + 768 + 8192) * sizeof(int), stream);

    // bucketed CSR build
    bucket_hist<<<NSB, 1024, 0, stream>>>(dstv, bcount);
    bucket_scan<<<1, 512, 0, stream>>>(bcount, bbase, bcursor);
    pair_scatter<<<NSB, 1024, 0, stream>>>(srcv, dstv, bcursor, pairs);
    bucket_build<<<NBUCK, 256, 0, stream>>>(pairs, bbase, rowptr, col);

    // pack weights (single bf16 plane, fragment order); convert x to bf16
    pack_w<<<dim3(8, 3), 256, 0, stream>>>(W1, Wp, 0);
    pack_w<<<dim3(8, 3), 256, 0, stream>>>(W2, Wp, 1);
    f2bf<<<NN * 16 / 256, 256, 0, stream>>>(x, B0);

    const int nmlp = (NN + 63) / 64;
    for (int l = 0; l < 3; ++l) {
        agg_bf<<<NN / 8, 256, 0, stream>>>(B0, rowptr, col, S0);
        mlp_v2<<<nmlp, 256, 0, stream>>>(S0, Wp + (size_t)(2 * l) * 16384, b1 + l * HID,
                                         Wp + (size_t)(2 * l + 1) * 16384, b2 + l * HID, B0,
                                         stats + l * 256);
        if (l < 2)
            bn_relu_bf<<<NN * 16 / 256, 256, 0, stream>>>(B0, stats + l * 256, gamma + l * HID, beta + l * HID);
    }
    bn_relu_out<<<NN * 32 / 256, 256, 0, stream>>>(B0, stats + 512, gamma + 2 * HID, beta + 2 * HID, out);

    find_starts<<<1, 128, 0, stream>>>(batch, starts);
    pool_partial<<<dim3(NG, 8), 128, 0, stream>>>(out, starts, gsum);
    pool_final<<<NG, 128, 0, stream>>>(gsum, starts, outG);
}